// Round 3
// baseline (167.553 us; speedup 1.0000x reference)
//
#include <hip/hip_runtime.h>
#include <math.h>

typedef __attribute__((ext_vector_type(8))) short short8;
typedef __attribute__((ext_vector_type(4))) float float4v;
typedef __attribute__((ext_vector_type(4))) unsigned short ushort4v;

static __device__ __forceinline__ unsigned short f2bf(float f) {
    union { float f; unsigned u; } v; v.f = f;
    unsigned u = v.u;
    return (unsigned short)((u + 0x7fffu + ((u >> 16) & 1u)) >> 16);
}
static __device__ __forceinline__ unsigned pk2(float a, float b) {
    return (unsigned)f2bf(a) | ((unsigned)f2bf(b) << 16);
}

// ---------------------------------------------------------------------------
// Graph structure (compile-time), matching Python enumeration order.
// ---------------------------------------------------------------------------
struct AdjT {
    int src[120];
    int dst[120];
    int cnt[36];
    int idx[36][4];
    int ostart[36];
    int ocnt[36];
};

constexpr AdjT build_adj() {
    AdjT a{};
    const int ddx[4] = {-1, 0, 0, 1};
    const int ddy[4] = {0, -1, 1, 0};
    int ne = 0;
    for (int i = 0; i < 6; i++)
        for (int j = 0; j < 6; j++)
            for (int d = 0; d < 4; d++) {
                int x = i + ddx[d], y = j + ddy[d];
                if (x >= 0 && x < 6 && y >= 0 && y < 6) {
                    a.src[ne] = j * 6 + i;
                    a.dst[ne] = y * 6 + x;
                    ne++;
                }
            }
    for (int n = 0; n < 36; n++) {
        a.cnt[n] = 0;
        for (int e = 0; e < 120; e++)
            if (a.dst[e] == n) a.idx[n][a.cnt[n]++] = e;
    }
    for (int n = 0; n < 36; n++) { a.ostart[n] = 0; a.ocnt[n] = 0; }
    for (int e = 0; e < 120; e++) {
        a.ocnt[a.src[e]]++;
        if (e == 0 || a.src[e] != a.src[e - 1]) a.ostart[a.src[e]] = e;
    }
    return a;
}

__device__ constexpr AdjT ADJC = build_adj();
__device__ constexpr int G16_START[17] =
    {0, 3, 6, 9, 12, 14, 16, 18, 20, 22, 24, 26, 28, 30, 32, 34, 36};

// ---------------------------------------------------------------------------
// K0: merged prep. Blocks 0..31: composite conv1∘conv2 weights, NEW R18
// K-layout: t = ks*32 + q*8 + j -> (row = t>>4, dx = t&15); valid row<9,dx<9,
// pads written as 0 (NaN-safe vs garbage A). 5 K-steps (K=160).
// Blocks 32..1319: elementwise B-frag prep for conv3/conv4 + heads (as R15).
// ---------------------------------------------------------------------------
__global__ __launch_bounds__(256) void k_prepall(
    const float* __restrict__ w1, const float* __restrict__ b1,
    const float* __restrict__ w2, const float* __restrict__ b2,
    const float* __restrict__ w3, const float* __restrict__ w4,
    const float* __restrict__ cnw1, const float* __restrict__ epw1,
    const float* __restrict__ cnw2, const float* __restrict__ epw2,
    unsigned short* __restrict__ wpc, float* __restrict__ wcb,
    unsigned short* __restrict__ wp3, unsigned short* __restrict__ wp4,
    unsigned short* __restrict__ wph1, unsigned short* __restrict__ wpcn2,
    unsigned short* __restrict__ wpep2) {
    __shared__ float s_w1[800];
    __shared__ float s_w2[800];
    if (blockIdx.x < 32) {
        const int co = blockIdx.x, tid = threadIdx.x;
        for (int i = tid; i < 800; i += 256) {
            s_w1[i] = w1[i];
            s_w2[i] = w2[co * 800 + i];
        }
        __syncthreads();
        if (tid < 160) {
            int t = tid;
            int ty = t >> 4, tx = t & 15;   // row, dx in new layout
            float val = 0.f;
            if (ty < 9 && tx < 9) {
                int ylo = ty > 4 ? ty - 4 : 0, yhi = ty < 4 ? ty : 4;
                int xlo = tx > 4 ? tx - 4 : 0, xhi = tx < 4 ? tx : 4;
                for (int k1y = ylo; k1y <= yhi; k1y++)
                    for (int k1x = xlo; k1x <= xhi; k1x++) {
                        int o1 = k1y * 5 + k1x;
                        int o2 = (ty - k1y) * 5 + (tx - k1x);
#pragma unroll
                        for (int ci = 0; ci < 32; ci++)
                            val += s_w1[ci * 25 + o1] * s_w2[ci * 25 + o2];
                    }
            }
            int n = co >> 1, nt = co & 1;
            int ks = t >> 5, r = t & 31, q = r >> 3, j = r & 7;
            wpc[ks * 1024 + nt * 512 + (q * 16 + n) * 8 + j] = f2bf(val);
        } else if (tid == 160) {
            float s = b2[co];
            for (int ci = 0; ci < 32; ci++) {
                float ws = 0.f;
#pragma unroll
                for (int t2 = 0; t2 < 25; t2++) ws += s_w2[ci * 25 + t2];
                s += b1[ci] * ws;
            }
            wcb[co] = s;
        }
        return;
    }
    int e = (blockIdx.x - 32) * 256 + threadIdx.x;
    if (e < 51200) {
        int j = e & 7, lane = (e >> 3) & 63, nt = (e >> 9) & 3, t = e >> 11;
        int co = 4 * (lane & 15) + nt, ci = (lane >> 4) * 8 + j;
        wp3[e] = f2bf(w3[(co * 32 + ci) * 25 + t]);
    } else if (e < 153600) {
        int e4 = e - 51200;
        int j = e4 & 7, lane = (e4 >> 3) & 63, nt = (e4 >> 9) & 3;
        int ks = (e4 >> 11) & 1, t = e4 >> 12;
        int co = 4 * (lane & 15) + nt, ci = ks * 32 + (lane >> 4) * 8 + j;
        wp4[e4] = f2bf(w4[(co * 64 + ci) * 25 + t]);
    } else {
        int eh = e - 153600;
        if (eh < 131072) {
            int j = eh & 7, lane = (eh >> 3) & 63, nt = (eh >> 9) & 31, kt = eh >> 14;
            int c = nt * 16 + (lane & 15);
            int k = kt * 32 + ((lane >> 4) << 3) + j;
            float v = (c < 256) ? cnw1[c * 256 + k] : epw1[(c - 256) * 256 + k];
            wph1[eh] = f2bf(v);
        } else if (eh < 163840) {
            int e2 = eh - 131072;
            int j = e2 & 7, lane = (e2 >> 3) & 63, nt = (e2 >> 9) & 7, kt = e2 >> 12;
            int c = nt * 16 + (lane & 15);
            int k = kt * 32 + ((lane >> 4) << 3) + j;
            wpcn2[e2] = f2bf(c < 120 ? cnw2[c * 256 + k] : 0.f);
        } else {
            int e3 = eh - 163840;
            int j = e3 & 7, lane = (e3 >> 3) & 63, idx = e3 >> 9;
            int kt = idx / 3, nt = idx - kt * 3;
            int c = nt * 16 + (lane & 15);
            int k = kt * 32 + ((lane >> 4) << 3) + j;
            wpep2[e3] = f2bf(c < 36 ? epw2[c * 256 + k] : 0.f);
        }
    }
}

// ---------------------------------------------------------------------------
// K_CONVALL (R18): back to 2 img/block (R16 occupancy) + 3 pipe fixes:
// (1) composite A via 4 shift-copies + ds_read_b64 pairs (K=160 row-major
//     taps; pads B=0; copies zero-padded so no junk*0=NaN),
// (2) conv3 wave=(mt-pair,nt-pair) over BOTH imgs: 8 MFMA / (4 LDS + 2 VMEM),
// (3) conv4 wave=nt over BOTH imgs: each unique B-frag loaded once/block.
// Per-img region (10560 ush): p2 [144][40] @ [0,5760); copies 4x1200 @ 5760
// (dead after composite) overlaid by c3 [64][72] @ [5760,10368); c4 f32
// [16][68] overlays p2.
// ---------------------------------------------------------------------------
#define REGSZ 10560
#define C3O 5760

__global__ __launch_bounds__(512) void k_convall(
    const float* __restrict__ img,
    const unsigned short* __restrict__ wpc, const float* __restrict__ wcb,
    const unsigned short* __restrict__ wp3, const float* __restrict__ b3,
    const unsigned short* __restrict__ wp4, const float* __restrict__ b4,
    unsigned short* __restrict__ emb) {
    __shared__ __align__(16) unsigned short s_buf[2 * REGSZ];
    const int b2 = blockIdx.x, tid = threadIdx.x;
    const int lane = tid & 63, wave = tid >> 6;
    const int m = lane & 15, quad = lane >> 4;

    // ---- stage both images as 4 shifted bf16 copies (36-stride rows) ----
    {
        int simg = tid >> 8, t = tid & 255;
        float4 v = ((const float4*)(img + (size_t)(2 * b2 + simg) * 1024))[t];
        unsigned short pv[4];
        pv[0] = f2bf(v.x); pv[1] = f2bf(v.y);
        pv[2] = f2bf(v.z); pv[3] = f2bf(v.w);
        int r = t >> 3, x0 = (t & 7) * 4;
        int p36 = r * 36 + x0;
        unsigned short* reg = s_buf + simg * REGSZ + C3O;
#pragma unroll
        for (int c = 0; c < 4; c++)
#pragma unroll
            for (int i = 0; i < 4; i++) {
                int pos = p36 + i - c;
                if (pos >= 0) reg[c * 1200 + pos] = pv[i];
            }
    }
    // zero-fill pad cols (x 32..35, r<32) + virtual rows 32..33 in all copies
    // (so pad-tap reads are finite; B=0 there makes them contribute 0)
    if (tid < 400) {
        int simg = tid >= 200, zz = tid - 200 * simg;
        int r, x;
        if (zz < 128) { r = zz >> 2; x = 32 + (zz & 3); }
        else { int rr = zz - 128; r = 32 + (rr >= 36 ? 1 : 0); x = rr - (rr >= 36 ? 36 : 0); }
        int p36 = r * 36 + x;
        unsigned short* reg = s_buf + simg * REGSZ + C3O;
#pragma unroll
        for (int c = 0; c < 4; c++) {
            int pos = p36 - c;
            if (pos >= 0 && pos < 1200) reg[c * 1200 + pos] = 0;
        }
    }

    // composite-conv B-frags (5 K-steps, held in regs) + bias + A offsets
    const short8* wqc = (const short8*)wpc;
    short8 cb0[5], cb1[5];
#pragma unroll
    for (int ks = 0; ks < 5; ks++) {
        cb0[ks] = wqc[(ks * 2 + 0) * 64 + lane];
        cb1[ks] = wqc[(ks * 2 + 1) * 64 + lane];
    }
    const float bc0 = wcb[2 * m], bc1 = wcb[2 * m + 1];
    int ct2[5];
#pragma unroll
    for (int ks = 0; ks < 5; ks++) {
        int t0 = ks * 32 + quad * 8;
        ct2[ks] = (t0 >> 4) * 36 + (t0 & 15);
    }
    const short8* wq3 = (const short8*)wp3;

    __syncthreads();

    // ---- composite conv + in-register pool -> p2 [144][40] x 2 images ----
    for (int TT = wave; TT < 72; TT += 8) {
        int ci = TT >= 36 ? 1 : 0;
        int T = TT - 36 * ci;
        int pg = T * 4 + (m >> 2);            // pooled output index 0..143
        int py = (pg * 171) >> 11;            // == pg/12 for pg<144
        int px = pg - py * 12;
        int albase = (2 * py + ((m & 3) >> 1)) * 36 + 2 * px + (m & 1);
        const unsigned short* reg = s_buf + ci * REGSZ + C3O;
        float4v a0 = {0.f, 0.f, 0.f, 0.f};
        float4v a1 = {0.f, 0.f, 0.f, 0.f};
#pragma unroll
        for (int ks = 0; ks < 5; ks++) {
            int a = albase + ct2[ks];
            int c = a & 3;
            const unsigned short* cp = reg + c * 1200 + (a - c);
            ushort4v lo = *(const ushort4v*)cp;
            ushort4v hi = *(const ushort4v*)(cp + 4);
            short8 av;
            av[0] = (short)lo[0]; av[1] = (short)lo[1];
            av[2] = (short)lo[2]; av[3] = (short)lo[3];
            av[4] = (short)hi[0]; av[5] = (short)hi[1];
            av[6] = (short)hi[2]; av[7] = (short)hi[3];
            a0 = __builtin_amdgcn_mfma_f32_16x16x32_bf16(av, cb0[ks], a0, 0, 0, 0);
            a1 = __builtin_amdgcn_mfma_f32_16x16x32_bf16(av, cb1[ks], a1, 0, 0, 0);
        }
        float mx0 = fmaxf(fmaxf(a0[0], a0[1]), fmaxf(a0[2], a0[3])) + bc0;
        float mx1 = fmaxf(fmaxf(a1[0], a1[1]), fmaxf(a1[2], a1[3])) + bc1;
        int row = T * 4 + quad;
        *(unsigned*)(s_buf + ci * REGSZ + row * 40 + 2 * m) = pk2(mx0, mx1);
    }
    __syncthreads();

    // ---- conv3: waves 0-3 = (mt-pair, nt-pair), both imgs; 8 MFMA/tap ----
    if (wave < 4) {
        const int mp = wave >> 1, np = wave & 1;
        int a3[2];
#pragma unroll
        for (int mi = 0; mi < 2; mi++) {
            int pos3 = (2 * mp + mi) * 16 + m;
            int y3 = pos3 >> 3, x3 = pos3 & 7;
            a3[mi] = (y3 * 12 + x3) * 40 + quad * 8;
        }
        float4v acc3[2][2][2];   // [img][mi][ni]
#pragma unroll
        for (int im = 0; im < 2; im++)
#pragma unroll
            for (int mi = 0; mi < 2; mi++)
#pragma unroll
                for (int ni = 0; ni < 2; ni++)
                    acc3[im][mi][ni] = (float4v){0.f, 0.f, 0.f, 0.f};
        short8 bA0 = wq3[(0 * 4 + 2 * np) * 64 + lane];
        short8 bA1 = wq3[(0 * 4 + 2 * np + 1) * 64 + lane];
        short8 bB0 = wq3[(1 * 4 + 2 * np) * 64 + lane];
        short8 bB1 = wq3[(1 * 4 + 2 * np + 1) * 64 + lane];
        for (int t = 0; t < 25; t++) {
            short8 bC0, bC1;
            if (t < 23) {
                bC0 = wq3[((t + 2) * 4 + 2 * np) * 64 + lane];
                bC1 = wq3[((t + 2) * 4 + 2 * np + 1) * 64 + lane];
            }
            const int ky = t / 5, kx = t - ky * 5;
            const int toff = (ky * 12 + kx) * 40;
            short8 av00 = *(const short8*)(s_buf + a3[0] + toff);
            short8 av01 = *(const short8*)(s_buf + a3[1] + toff);
            short8 av10 = *(const short8*)(s_buf + REGSZ + a3[0] + toff);
            short8 av11 = *(const short8*)(s_buf + REGSZ + a3[1] + toff);
            acc3[0][0][0] = __builtin_amdgcn_mfma_f32_16x16x32_bf16(av00, bA0, acc3[0][0][0], 0, 0, 0);
            acc3[0][0][1] = __builtin_amdgcn_mfma_f32_16x16x32_bf16(av00, bA1, acc3[0][0][1], 0, 0, 0);
            acc3[0][1][0] = __builtin_amdgcn_mfma_f32_16x16x32_bf16(av01, bA0, acc3[0][1][0], 0, 0, 0);
            acc3[0][1][1] = __builtin_amdgcn_mfma_f32_16x16x32_bf16(av01, bA1, acc3[0][1][1], 0, 0, 0);
            acc3[1][0][0] = __builtin_amdgcn_mfma_f32_16x16x32_bf16(av10, bA0, acc3[1][0][0], 0, 0, 0);
            acc3[1][0][1] = __builtin_amdgcn_mfma_f32_16x16x32_bf16(av10, bA1, acc3[1][0][1], 0, 0, 0);
            acc3[1][1][0] = __builtin_amdgcn_mfma_f32_16x16x32_bf16(av11, bA0, acc3[1][1][0], 0, 0, 0);
            acc3[1][1][1] = __builtin_amdgcn_mfma_f32_16x16x32_bf16(av11, bA1, acc3[1][1][1], 0, 0, 0);
            bA0 = bB0; bA1 = bB1;
            if (t < 23) { bB0 = bC0; bB1 = bC1; }
        }
        float bb0 = b3[4 * m + 2 * np], bb1 = b3[4 * m + 2 * np + 1];
#pragma unroll
        for (int im = 0; im < 2; im++)
#pragma unroll
            for (int mi = 0; mi < 2; mi++)
#pragma unroll
                for (int r = 0; r < 4; r++) {
                    int row3 = (2 * mp + mi) * 16 + quad * 4 + r;
                    *(unsigned*)(s_buf + im * REGSZ + C3O + row3 * 72 + 4 * m + 2 * np) =
                        pk2(acc3[im][mi][0][r] + bb0, acc3[im][mi][1][r] + bb1);
                }
    }
    __syncthreads();

    // ---- conv4: waves 0-3 = nt, both imgs; each B-frag loaded once ----
    if (wave < 4) {
        const int nt4 = wave;
        int y4 = m >> 2, x4 = m & 3;
        int a4 = C3O + (y4 * 8 + x4) * 72 + quad * 8;
        float4v acc4[2];
        acc4[0] = (float4v){0.f, 0.f, 0.f, 0.f};
        acc4[1] = (float4v){0.f, 0.f, 0.f, 0.f};
        const short8* wq4 = (const short8*)wp4;
        short8 cA0 = wq4[((0 * 2 + 0) * 4 + nt4) * 64 + lane];
        short8 cA1 = wq4[((0 * 2 + 1) * 4 + nt4) * 64 + lane];
        short8 cB0 = wq4[((1 * 2 + 0) * 4 + nt4) * 64 + lane];
        short8 cB1 = wq4[((1 * 2 + 1) * 4 + nt4) * 64 + lane];
        for (int t = 0; t < 25; t++) {
            short8 cC0, cC1;
            if (t < 23) {
                cC0 = wq4[(((t + 2) * 2 + 0) * 4 + nt4) * 64 + lane];
                cC1 = wq4[(((t + 2) * 2 + 1) * 4 + nt4) * 64 + lane];
            }
            const int ky = t / 5, kx = t - ky * 5;
            const int toff = (ky * 8 + kx) * 72;
            short8 a00 = *(const short8*)(s_buf + a4 + toff);
            short8 a01 = *(const short8*)(s_buf + a4 + toff + 32);
            short8 a10 = *(const short8*)(s_buf + REGSZ + a4 + toff);
            short8 a11 = *(const short8*)(s_buf + REGSZ + a4 + toff + 32);
            acc4[0] = __builtin_amdgcn_mfma_f32_16x16x32_bf16(a00, cA0, acc4[0], 0, 0, 0);
            acc4[0] = __builtin_amdgcn_mfma_f32_16x16x32_bf16(a01, cA1, acc4[0], 0, 0, 0);
            acc4[1] = __builtin_amdgcn_mfma_f32_16x16x32_bf16(a10, cA0, acc4[1], 0, 0, 0);
            acc4[1] = __builtin_amdgcn_mfma_f32_16x16x32_bf16(a11, cA1, acc4[1], 0, 0, 0);
            cA0 = cB0; cA1 = cB1;
            if (t < 23) { cB0 = cC0; cB1 = cC1; }
        }
#pragma unroll
        for (int im = 0; im < 2; im++) {
            float* s_c4 = (float*)(s_buf + im * REGSZ);
#pragma unroll
            for (int r = 0; r < 4; r++)
                s_c4[(quad * 4 + r) * 68 + 4 * m + nt4] = acc4[im][r];
        }
    }
    __syncthreads();

    // emb epilogue: tid = img*256 + co*4 + pp; pool 2x2 + bias4 + flatten
    {
        const int simg = tid >> 8, t = tid & 255;
        const float* s_c4 = (const float*)(s_buf + simg * REGSZ);
        int co = t >> 2, pp = t & 3;
        int ppy = pp >> 1, ppx = pp & 1;
        float v0 = s_c4[((2 * ppy) * 4 + 2 * ppx) * 68 + co];
        float v1 = s_c4[((2 * ppy) * 4 + 2 * ppx + 1) * 68 + co];
        float v2 = s_c4[((2 * ppy + 1) * 4 + 2 * ppx) * 68 + co];
        float v3 = s_c4[((2 * ppy + 1) * 4 + 2 * ppx + 1) * 68 + co];
        emb[(size_t)(2 * b2 + simg) * 256 + t] =
            f2bf(fmaxf(fmaxf(v0, v1), fmaxf(v2, v3)) + b4[co]);
    }
}

// ---------------------------------------------------------------------------
// K5: fused heads (MFMA) + DAMP recurrence (verified R4-R14, unchanged).
// ---------------------------------------------------------------------------
__global__ __launch_bounds__(256) void k_heads(
    const unsigned short* __restrict__ emb,
    const unsigned short* __restrict__ wph1,
    const float* __restrict__ cn_b1, const float* __restrict__ ep_b1,
    const unsigned short* __restrict__ wpcn2, const float* __restrict__ cn_b2,
    const unsigned short* __restrict__ wpep2, const float* __restrict__ ep_b2,
    float* __restrict__ out) {
    __shared__ unsigned short s_hid[16 * 520];
    __shared__ float s_conn[120 * 17];
    __shared__ float s_rec0[120 * 17];
    __shared__ float s_rec1[120 * 17];
    __shared__ float s_ep[36 * 17];
    const int tid = threadIdx.x;
    const int lane = tid & 63, wave = tid >> 6;
    const int m = lane & 15, q = lane >> 4;
    const int b0 = blockIdx.x * 16;

    float4v acc[8];
#pragma unroll
    for (int i = 0; i < 8; i++) acc[i] = (float4v){0.f, 0.f, 0.f, 0.f};
    const short8* wp1 = (const short8*)wph1;
    for (int kt = 0; kt < 8; kt++) {
        short8 av = *(const short8*)(emb + (size_t)(b0 + m) * 256 + kt * 32 + q * 8);
#pragma unroll
        for (int ntl = 0; ntl < 8; ntl++) {
            int nt = wave * 8 + ntl;
            short8 bv = wp1[(kt * 32 + nt) * 64 + lane];
            acc[ntl] = __builtin_amdgcn_mfma_f32_16x16x32_bf16(av, bv, acc[ntl], 0, 0, 0);
        }
    }
#pragma unroll
    for (int ntl = 0; ntl < 8; ntl++) {
        int c = (wave * 8 + ntl) * 16 + m;
        float bb = (c < 256) ? cn_b1[c] : ep_b1[c - 256];
#pragma unroll
        for (int r = 0; r < 4; r++)
            s_hid[(q * 4 + r) * 520 + c] = f2bf(fmaxf(acc[ntl][r] + bb, 0.f));
    }
    __syncthreads();

    for (int job = wave; job < 11; job += 4) {
        const bool isconn = job < 8;
        const int koff = isconn ? 0 : 256;
        float4v a2 = (float4v){0.f, 0.f, 0.f, 0.f};
        for (int kt = 0; kt < 8; kt++) {
            short8 av = *(const short8*)(s_hid + m * 520 + koff + kt * 32 + q * 8);
            short8 bv = isconn
                ? ((const short8*)wpcn2)[(kt * 8 + job) * 64 + lane]
                : ((const short8*)wpep2)[(kt * 3 + (job - 8)) * 64 + lane];
            a2 = __builtin_amdgcn_mfma_f32_16x16x32_bf16(av, bv, a2, 0, 0, 0);
        }
        int c = (isconn ? job : (job - 8)) * 16 + m;
        float bb = isconn ? (c < 120 ? cn_b2[c] : 0.f) : (c < 36 ? ep_b2[c] : 0.f);
#pragma unroll
        for (int r = 0; r < 4; r++) {
            float v = 1.f / (1.f + __expf(-(a2[r] + bb)));
            int row = q * 4 + r;
            if (isconn) {
                if (c < 120) { s_conn[c * 17 + row] = v; s_rec0[c * 17 + row] = v; }
            } else {
                if (c < 36) s_ep[c * 17 + row] = v;
            }
        }
    }
    __syncthreads();

    const int row = tid >> 4, g = tid & 15;
    const int ns = G16_START[g];
    const int nodecnt = G16_START[g + 1] - ns;
    int ie[3][4], icnt[3], os[3], oc[3];
    float cr[3][4];
#pragma unroll
    for (int s = 0; s < 3; s++) {
        if (s < nodecnt) {
            int n = ns + s;
            icnt[s] = ADJC.cnt[n];
#pragma unroll
            for (int qx = 0; qx < 4; qx++) ie[s][qx] = ADJC.idx[n][qx];
            os[s] = ADJC.ostart[n];
            oc[s] = ADJC.ocnt[n];
#pragma unroll
            for (int oe = 0; oe < 4; oe++)
                cr[s][oe] = (oe < oc[s]) ? s_conn[(os[s] + oe) * 17 + row] : 0.f;
        } else {
            icnt[s] = 0; oc[s] = 0; os[s] = 0;
#pragma unroll
            for (int qx = 0; qx < 4; qx++) ie[s][qx] = 0;
#pragma unroll
            for (int oe = 0; oe < 4; oe++) cr[s][oe] = 0.f;
        }
    }
    float old0 = (g == 0) ? s_conn[0 * 17 + row] : 0.f;

    for (int it = 0; it < 36; it++) {
        const float* cur = (it & 1) ? s_rec1 : s_rec0;
        float* nxt = (it & 1) ? s_rec0 : s_rec1;
#pragma unroll
        for (int s = 0; s < 3; s++) {
            float sum = 0.f;
#pragma unroll
            for (int qx = 0; qx < 4; qx++)
                sum += (qx < icnt[s]) ? cur[ie[s][qx] * 17 + row] : 0.f;
            sum = fminf(sum, 1.f);
#pragma unroll
            for (int oe = 0; oe < 4; oe++) {
                if (oe < oc[s]) {
                    int e = os[s] + oe;
                    float nv = sum * cr[s][oe];
                    nxt[e * 17 + row] = nv;
                    if (g == 0 && s == 0 && oe == 0)
                        old0 = fminf(old0 + nv, 1.f);
                }
            }
        }
        __asm__ volatile("s_waitcnt lgkmcnt(0)" ::: "memory");
    }

    if (g == 0)
        out[b0 + row] = old0 * s_ep[0 * 17 + row] * s_ep[6 * 17 + row];
}

// ---------------------------------------------------------------------------
extern "C" void kernel_launch(void* const* d_in, const int* in_sizes, int n_in,
                              void* d_out, int out_size, void* d_ws, size_t ws_size,
                              hipStream_t stream) {
    const float* image = (const float*)d_in[0];
    const float* c1w = (const float*)d_in[1];
    const float* c1b = (const float*)d_in[2];
    const float* c2w = (const float*)d_in[3];
    const float* c2b = (const float*)d_in[4];
    const float* c3w = (const float*)d_in[5];
    const float* c3b = (const float*)d_in[6];
    const float* c4w = (const float*)d_in[7];
    const float* c4b = (const float*)d_in[8];
    const float* epw1 = (const float*)d_in[9];
    const float* epb1 = (const float*)d_in[10];
    const float* epw2 = (const float*)d_in[11];
    const float* epb2 = (const float*)d_in[12];
    const float* cnw1 = (const float*)d_in[13];
    const float* cnb1 = (const float*)d_in[14];
    const float* cnw2 = (const float*)d_in[15];
    const float* cnb2 = (const float*)d_in[16];

    const int B = in_sizes[0] / (32 * 32);  // 1024

    unsigned short* ws = (unsigned short*)d_ws;
    unsigned short* embo = ws;                            // B*256 bf16
    unsigned short* wp3 = embo + (size_t)B * 256;         // 51200
    unsigned short* wp4 = wp3 + 51200;                    // 102400
    unsigned short* wph1 = wp4 + 102400;                  // 131072
    unsigned short* wpcn2 = wph1 + 131072;                // 32768
    unsigned short* wpep2 = wpcn2 + 32768;                // 12288
    unsigned short* wpc = wpep2 + 12288;                  // 5120 (K=160)
    float* wcb = (float*)(wpc + 5120);                    // 32 f32

    k_prepall<<<1320, 256, 0, stream>>>(c1w, c1b, c2w, c2b, c3w, c4w,
                                        cnw1, epw1, cnw2, epw2,
                                        wpc, wcb, wp3, wp4, wph1, wpcn2, wpep2);
    k_convall<<<B / 2, 512, 0, stream>>>(image, wpc, wcb, wp3, c3b, wp4, c4b, embo);
    k_heads<<<B / 16, 256, 0, stream>>>(embo, wph1, cnb1, epb1,
                                        wpcn2, cnb2, wpep2, epb2, (float*)d_out);
}

// Round 4
// 161.644 us; speedup vs baseline: 1.0366x; 1.0366x over previous
//
#include <hip/hip_runtime.h>
#include <math.h>

typedef __attribute__((ext_vector_type(8))) short short8;
typedef __attribute__((ext_vector_type(4))) float float4v;
typedef __attribute__((ext_vector_type(4))) unsigned short ushort4v;

static __device__ __forceinline__ unsigned short f2bf(float f) {
    union { float f; unsigned u; } v; v.f = f;
    unsigned u = v.u;
    return (unsigned short)((u + 0x7fffu + ((u >> 16) & 1u)) >> 16);
}
static __device__ __forceinline__ unsigned pk2(float a, float b) {
    return (unsigned)f2bf(a) | ((unsigned)f2bf(b) << 16);
}

// ---------------------------------------------------------------------------
// Graph structure (compile-time), matching Python enumeration order.
// ---------------------------------------------------------------------------
struct AdjT {
    int src[120];
    int dst[120];
    int cnt[36];
    int idx[36][4];
    int ostart[36];
    int ocnt[36];
};

constexpr AdjT build_adj() {
    AdjT a{};
    const int ddx[4] = {-1, 0, 0, 1};
    const int ddy[4] = {0, -1, 1, 0};
    int ne = 0;
    for (int i = 0; i < 6; i++)
        for (int j = 0; j < 6; j++)
            for (int d = 0; d < 4; d++) {
                int x = i + ddx[d], y = j + ddy[d];
                if (x >= 0 && x < 6 && y >= 0 && y < 6) {
                    a.src[ne] = j * 6 + i;
                    a.dst[ne] = y * 6 + x;
                    ne++;
                }
            }
    for (int n = 0; n < 36; n++) {
        a.cnt[n] = 0;
        for (int e = 0; e < 120; e++)
            if (a.dst[e] == n) a.idx[n][a.cnt[n]++] = e;
    }
    for (int n = 0; n < 36; n++) { a.ostart[n] = 0; a.ocnt[n] = 0; }
    for (int e = 0; e < 120; e++) {
        a.ocnt[a.src[e]]++;
        if (e == 0 || a.src[e] != a.src[e - 1]) a.ostart[a.src[e]] = e;
    }
    return a;
}

__device__ constexpr AdjT ADJC = build_adj();
__device__ constexpr int G16_START[17] =
    {0, 3, 6, 9, 12, 14, 16, 18, 20, 22, 24, 26, 28, 30, 32, 34, 36};

// ---------------------------------------------------------------------------
// K0: merged prep. Blocks 0..31: composite conv1∘conv2 weights, R19 K-layout:
// rows-of-12 -> t in [0,128): (ty,tx) = (t/12, t%12); valid ty<9 && tx<9,
// pad slots written 0 (NaN-safe). K=128, 4 K-steps.
// Blocks 32..1319: elementwise B-frag prep for conv3/conv4 + heads (as R15).
// ---------------------------------------------------------------------------
__global__ __launch_bounds__(256) void k_prepall(
    const float* __restrict__ w1, const float* __restrict__ b1,
    const float* __restrict__ w2, const float* __restrict__ b2,
    const float* __restrict__ w3, const float* __restrict__ w4,
    const float* __restrict__ cnw1, const float* __restrict__ epw1,
    const float* __restrict__ cnw2, const float* __restrict__ epw2,
    unsigned short* __restrict__ wpc, float* __restrict__ wcb,
    unsigned short* __restrict__ wp3, unsigned short* __restrict__ wp4,
    unsigned short* __restrict__ wph1, unsigned short* __restrict__ wpcn2,
    unsigned short* __restrict__ wpep2) {
    __shared__ float s_w1[800];
    __shared__ float s_w2[800];
    if (blockIdx.x < 32) {
        const int co = blockIdx.x, tid = threadIdx.x;
        for (int i = tid; i < 800; i += 256) {
            s_w1[i] = w1[i];
            s_w2[i] = w2[co * 800 + i];
        }
        __syncthreads();
        if (tid < 128) {
            int t = tid;
            int ty = t / 12, tx = t - 12 * ty;
            float val = 0.f;
            if (ty < 9 && tx < 9) {
                int ylo = ty > 4 ? ty - 4 : 0, yhi = ty < 4 ? ty : 4;
                int xlo = tx > 4 ? tx - 4 : 0, xhi = tx < 4 ? tx : 4;
                for (int k1y = ylo; k1y <= yhi; k1y++)
                    for (int k1x = xlo; k1x <= xhi; k1x++) {
                        int o1 = k1y * 5 + k1x;
                        int o2 = (ty - k1y) * 5 + (tx - k1x);
#pragma unroll
                        for (int ci = 0; ci < 32; ci++)
                            val += s_w1[ci * 25 + o1] * s_w2[ci * 25 + o2];
                    }
            }
            int n = co >> 1, nt = co & 1;
            int ks = t >> 5, r = t & 31, q = r >> 3, j = r & 7;
            wpc[ks * 1024 + nt * 512 + (q * 16 + n) * 8 + j] = f2bf(val);
        } else if (tid == 128) {
            float s = b2[co];
            for (int ci = 0; ci < 32; ci++) {
                float ws = 0.f;
#pragma unroll
                for (int t2 = 0; t2 < 25; t2++) ws += s_w2[ci * 25 + t2];
                s += b1[ci] * ws;
            }
            wcb[co] = s;
        }
        return;
    }
    int e = (blockIdx.x - 32) * 256 + threadIdx.x;
    if (e < 51200) {
        int j = e & 7, lane = (e >> 3) & 63, nt = (e >> 9) & 3, t = e >> 11;
        int co = 4 * (lane & 15) + nt, ci = (lane >> 4) * 8 + j;
        wp3[e] = f2bf(w3[(co * 32 + ci) * 25 + t]);
    } else if (e < 153600) {
        int e4 = e - 51200;
        int j = e4 & 7, lane = (e4 >> 3) & 63, nt = (e4 >> 9) & 3;
        int ks = (e4 >> 11) & 1, t = e4 >> 12;
        int co = 4 * (lane & 15) + nt, ci = ks * 32 + (lane >> 4) * 8 + j;
        wp4[e4] = f2bf(w4[(co * 64 + ci) * 25 + t]);
    } else {
        int eh = e - 153600;
        if (eh < 131072) {
            int j = eh & 7, lane = (eh >> 3) & 63, nt = (eh >> 9) & 31, kt = eh >> 14;
            int c = nt * 16 + (lane & 15);
            int k = kt * 32 + ((lane >> 4) << 3) + j;
            float v = (c < 256) ? cnw1[c * 256 + k] : epw1[(c - 256) * 256 + k];
            wph1[eh] = f2bf(v);
        } else if (eh < 163840) {
            int e2 = eh - 131072;
            int j = e2 & 7, lane = (e2 >> 3) & 63, nt = (e2 >> 9) & 7, kt = e2 >> 12;
            int c = nt * 16 + (lane & 15);
            int k = kt * 32 + ((lane >> 4) << 3) + j;
            wpcn2[e2] = f2bf(c < 120 ? cnw2[c * 256 + k] : 0.f);
        } else {
            int e3 = eh - 163840;
            int j = e3 & 7, lane = (e3 >> 3) & 63, idx = e3 >> 9;
            int kt = idx / 3, nt = idx - kt * 3;
            int c = nt * 16 + (lane & 15);
            int k = kt * 32 + ((lane >> 4) << 3) + j;
            wpep2[e3] = f2bf(c < 36 ? epw2[c * 256 + k] : 0.f);
        }
    }
}

// ---------------------------------------------------------------------------
// K_CONVALL (R19): R16 structure verbatim (2 img/block, 512 thr, all phases
// 8 waves) + ONE change: composite A-reads via 4 shifted image copies +
// rows-of-12 K=128 layout -> 8 ds_read_b64 per job (was 24 ds_read_u16).
// Per-img region (10656 ush): p2 [144][40] @ [0,5760); 4 shift-copies
// 4x1224 @ C3O (dead after composite) overlaid by c3 [64][72] @
// [5760,10368); c4 f32 [16][68] overlays p2 (dead after conv3).
// ---------------------------------------------------------------------------
#define REGSZ 10656
#define C3O 5760
#define CPY 1224

__global__ __launch_bounds__(512) void k_convall(
    const float* __restrict__ img,
    const unsigned short* __restrict__ wpc, const float* __restrict__ wcb,
    const unsigned short* __restrict__ wp3, const float* __restrict__ b3,
    const unsigned short* __restrict__ wp4, const float* __restrict__ b4,
    unsigned short* __restrict__ emb) {
    __shared__ __align__(16) unsigned short s_buf[2 * REGSZ];
    const int b2 = blockIdx.x, tid = threadIdx.x;
    const int lane = tid & 63, wave = tid >> 6;
    const int m = lane & 15, quad = lane >> 4;

    // ---- stage both images as 4 shifted bf16 copies (36-stride rows) ----
    {
        int simg = tid >> 8, t = tid & 255;
        float4 v = ((const float4*)(img + (size_t)(2 * b2 + simg) * 1024))[t];
        unsigned short pv[4];
        pv[0] = f2bf(v.x); pv[1] = f2bf(v.y);
        pv[2] = f2bf(v.z); pv[3] = f2bf(v.w);
        int r = t >> 3, x0 = (t & 7) * 4;
        int p36 = r * 36 + x0;
        unsigned short* reg = s_buf + simg * REGSZ + C3O;
#pragma unroll
        for (int c = 0; c < 4; c++)
#pragma unroll
            for (int i = 0; i < 4; i++) {
                int pos = p36 + i - c;
                if (pos >= 0) reg[c * CPY + pos] = pv[i];
            }
    }
    // zero-fill pad cols (x 32..35, r<32) + virtual rows 32..33 in all copies
    if (tid < 400) {
        int simg = tid >= 200, zz = tid - 200 * simg;
        int r, x;
        if (zz < 128) { r = zz >> 2; x = 32 + (zz & 3); }
        else { int rr = zz - 128; r = 32 + (rr >= 36 ? 1 : 0); x = rr - (rr >= 36 ? 36 : 0); }
        int p36 = r * 36 + x;
        unsigned short* reg = s_buf + simg * REGSZ + C3O;
#pragma unroll
        for (int c = 0; c < 4; c++) {
            int pos = p36 - c;
            if (pos >= 0 && pos < CPY) reg[c * CPY + pos] = 0;
        }
    }

    // composite-conv B-frags (4 K-steps, held in regs) + bias + A offsets
    const short8* wqc = (const short8*)wpc;
    short8 cb0[4], cb1[4];
#pragma unroll
    for (int ks = 0; ks < 4; ks++) {
        cb0[ks] = wqc[(ks * 2 + 0) * 64 + lane];
        cb1[ks] = wqc[(ks * 2 + 1) * 64 + lane];
    }
    const float bc0 = wcb[2 * m], bc1 = wcb[2 * m + 1];
    int ct1[4], ct2[4];
#pragma unroll
    for (int ks = 0; ks < 4; ks++) {
        int t0 = ks * 32 + quad * 8;
        ct1[ks] = (t0 / 12) * 36 + (t0 % 12);
        int t4 = t0 + 4;
        ct2[ks] = (t4 / 12) * 36 + (t4 % 12);
    }
    const short8* wq3 = (const short8*)wp3;

    __syncthreads();

    // ---- composite conv + in-register pool -> p2 [144][40] x 2 images ----
    for (int TT = wave; TT < 72; TT += 8) {
        int ci = TT >= 36 ? 1 : 0;
        int T = TT - 36 * ci;
        int pg = T * 4 + (m >> 2);            // pooled output index 0..143
        int py = (pg * 171) >> 11;            // == pg/12 for pg<144
        int px = pg - py * 12;
        int albase = (2 * py + ((m & 3) >> 1)) * 36 + 2 * px + (m & 1);
        const unsigned short* reg = s_buf + ci * REGSZ + C3O;
        float4v a0 = {0.f, 0.f, 0.f, 0.f};
        float4v a1 = {0.f, 0.f, 0.f, 0.f};
#pragma unroll
        for (int ks = 0; ks < 4; ks++) {
            int a = albase + ct1[ks];
            int c = a & 3;
            ushort4v lo = *(const ushort4v*)(reg + c * CPY + (a - c));
            a = albase + ct2[ks];
            c = a & 3;
            ushort4v hi = *(const ushort4v*)(reg + c * CPY + (a - c));
            short8 av;
            av[0] = (short)lo[0]; av[1] = (short)lo[1];
            av[2] = (short)lo[2]; av[3] = (short)lo[3];
            av[4] = (short)hi[0]; av[5] = (short)hi[1];
            av[6] = (short)hi[2]; av[7] = (short)hi[3];
            a0 = __builtin_amdgcn_mfma_f32_16x16x32_bf16(av, cb0[ks], a0, 0, 0, 0);
            a1 = __builtin_amdgcn_mfma_f32_16x16x32_bf16(av, cb1[ks], a1, 0, 0, 0);
        }
        float mx0 = fmaxf(fmaxf(a0[0], a0[1]), fmaxf(a0[2], a0[3])) + bc0;
        float mx1 = fmaxf(fmaxf(a1[0], a1[1]), fmaxf(a1[2], a1[3])) + bc1;
        int row = T * 4 + quad;
        *(unsigned*)(s_buf + ci * REGSZ + row * 40 + 2 * m) = pk2(mx0, mx1);
    }
    __syncthreads();

    // ---- conv3: wave = (img, Mtile-pair, Ntile-pair); 4 MFMA per tap (R16) ----
    {
        const int img3 = wave >> 2;
        const int mt0 = ((wave >> 1) & 1) * 2;
        const int nt0 = (wave & 1) * 2;
        const unsigned short* sb = s_buf + img3 * REGSZ;
        int a3[2];
#pragma unroll
        for (int mi = 0; mi < 2; mi++) {
            int pos3 = (mt0 + mi) * 16 + m;
            int y3 = pos3 >> 3, x3 = pos3 & 7;
            a3[mi] = (y3 * 12 + x3) * 40 + quad * 8;
        }
        float4v acc3[2][2];
#pragma unroll
        for (int mi = 0; mi < 2; mi++)
#pragma unroll
            for (int ni = 0; ni < 2; ni++)
                acc3[mi][ni] = (float4v){0.f, 0.f, 0.f, 0.f};
        short8 bw3[2];
        bw3[0] = wq3[nt0 * 64 + lane];
        bw3[1] = wq3[(nt0 + 1) * 64 + lane];
        for (int t = 0; t < 25; t++) {
            short8 nb3[2];
            if (t < 24) {
                nb3[0] = wq3[((t + 1) * 4 + nt0) * 64 + lane];
                nb3[1] = wq3[((t + 1) * 4 + nt0 + 1) * 64 + lane];
            }
            const int ky = t / 5, kx = t - ky * 5;
            const int toff = (ky * 12 + kx) * 40;
            short8 av0 = *(const short8*)(sb + a3[0] + toff);
            short8 av1 = *(const short8*)(sb + a3[1] + toff);
            acc3[0][0] = __builtin_amdgcn_mfma_f32_16x16x32_bf16(av0, bw3[0], acc3[0][0], 0, 0, 0);
            acc3[0][1] = __builtin_amdgcn_mfma_f32_16x16x32_bf16(av0, bw3[1], acc3[0][1], 0, 0, 0);
            acc3[1][0] = __builtin_amdgcn_mfma_f32_16x16x32_bf16(av1, bw3[0], acc3[1][0], 0, 0, 0);
            acc3[1][1] = __builtin_amdgcn_mfma_f32_16x16x32_bf16(av1, bw3[1], acc3[1][1], 0, 0, 0);
            if (t < 24) { bw3[0] = nb3[0]; bw3[1] = nb3[1]; }
        }
        float bb0 = b3[4 * m + nt0], bb1 = b3[4 * m + nt0 + 1];
#pragma unroll
        for (int mi = 0; mi < 2; mi++)
#pragma unroll
            for (int r = 0; r < 4; r++) {
                int row3 = (mt0 + mi) * 16 + quad * 4 + r;
                *(unsigned*)(s_buf + img3 * REGSZ + C3O + row3 * 72 + 4 * m + nt0) =
                    pk2(acc3[mi][0][r] + bb0, acc3[mi][1][r] + bb1);
            }
    }
    __syncthreads();

    // ---- conv4: wave = (img, Ntile); ALL 8 waves active (R16) ----
    {
        const int img4 = wave >> 2, nt4 = wave & 3;
        int y4 = m >> 2, x4 = m & 3;
        const unsigned short* sb = s_buf + img4 * REGSZ;
        int a4 = C3O + (y4 * 8 + x4) * 72 + quad * 8;
        float4v acc4 = (float4v){0.f, 0.f, 0.f, 0.f};
        const short8* wq4 = (const short8*)wp4;
        short8 cw0 = wq4[(0 * 4 + nt4) * 64 + lane];
        short8 cw1 = wq4[(1 * 4 + nt4) * 64 + lane];
        for (int t = 0; t < 25; t++) {
            short8 n0, n1;
            if (t < 24) {
                n0 = wq4[(((t + 1) * 2) * 4 + nt4) * 64 + lane];
                n1 = wq4[(((t + 1) * 2 + 1) * 4 + nt4) * 64 + lane];
            }
            const int ky = t / 5, kx = t - ky * 5;
            const int toff = (ky * 8 + kx) * 72;
            short8 av0 = *(const short8*)(sb + a4 + toff);
            acc4 = __builtin_amdgcn_mfma_f32_16x16x32_bf16(av0, cw0, acc4, 0, 0, 0);
            short8 av1 = *(const short8*)(sb + a4 + toff + 32);
            acc4 = __builtin_amdgcn_mfma_f32_16x16x32_bf16(av1, cw1, acc4, 0, 0, 0);
            if (t < 24) { cw0 = n0; cw1 = n1; }
        }
        float* s_c4 = (float*)(s_buf + img4 * REGSZ);
#pragma unroll
        for (int r = 0; r < 4; r++)
            s_c4[(quad * 4 + r) * 68 + 4 * m + nt4] = acc4[r];
    }
    __syncthreads();

    // emb epilogue: tid = img*256 + co*4 + pp; pool 2x2 + bias4 + flatten
    {
        const int simg = tid >> 8, t = tid & 255;
        const float* s_c4 = (const float*)(s_buf + simg * REGSZ);
        int co = t >> 2, pp = t & 3;
        int ppy = pp >> 1, ppx = pp & 1;
        float v0 = s_c4[((2 * ppy) * 4 + 2 * ppx) * 68 + co];
        float v1 = s_c4[((2 * ppy) * 4 + 2 * ppx + 1) * 68 + co];
        float v2 = s_c4[((2 * ppy + 1) * 4 + 2 * ppx) * 68 + co];
        float v3 = s_c4[((2 * ppy + 1) * 4 + 2 * ppx + 1) * 68 + co];
        emb[(size_t)(2 * b2 + simg) * 256 + t] =
            f2bf(fmaxf(fmaxf(v0, v1), fmaxf(v2, v3)) + b4[co]);
    }
}

// ---------------------------------------------------------------------------
// K5: fused heads (MFMA) + DAMP recurrence (verified R4-R14, unchanged).
// ---------------------------------------------------------------------------
__global__ __launch_bounds__(256) void k_heads(
    const unsigned short* __restrict__ emb,
    const unsigned short* __restrict__ wph1,
    const float* __restrict__ cn_b1, const float* __restrict__ ep_b1,
    const unsigned short* __restrict__ wpcn2, const float* __restrict__ cn_b2,
    const unsigned short* __restrict__ wpep2, const float* __restrict__ ep_b2,
    float* __restrict__ out) {
    __shared__ unsigned short s_hid[16 * 520];
    __shared__ float s_conn[120 * 17];
    __shared__ float s_rec0[120 * 17];
    __shared__ float s_rec1[120 * 17];
    __shared__ float s_ep[36 * 17];
    const int tid = threadIdx.x;
    const int lane = tid & 63, wave = tid >> 6;
    const int m = lane & 15, q = lane >> 4;
    const int b0 = blockIdx.x * 16;

    float4v acc[8];
#pragma unroll
    for (int i = 0; i < 8; i++) acc[i] = (float4v){0.f, 0.f, 0.f, 0.f};
    const short8* wp1 = (const short8*)wph1;
    for (int kt = 0; kt < 8; kt++) {
        short8 av = *(const short8*)(emb + (size_t)(b0 + m) * 256 + kt * 32 + q * 8);
#pragma unroll
        for (int ntl = 0; ntl < 8; ntl++) {
            int nt = wave * 8 + ntl;
            short8 bv = wp1[(kt * 32 + nt) * 64 + lane];
            acc[ntl] = __builtin_amdgcn_mfma_f32_16x16x32_bf16(av, bv, acc[ntl], 0, 0, 0);
        }
    }
#pragma unroll
    for (int ntl = 0; ntl < 8; ntl++) {
        int c = (wave * 8 + ntl) * 16 + m;
        float bb = (c < 256) ? cn_b1[c] : ep_b1[c - 256];
#pragma unroll
        for (int r = 0; r < 4; r++)
            s_hid[(q * 4 + r) * 520 + c] = f2bf(fmaxf(acc[ntl][r] + bb, 0.f));
    }
    __syncthreads();

    for (int job = wave; job < 11; job += 4) {
        const bool isconn = job < 8;
        const int koff = isconn ? 0 : 256;
        float4v a2 = (float4v){0.f, 0.f, 0.f, 0.f};
        for (int kt = 0; kt < 8; kt++) {
            short8 av = *(const short8*)(s_hid + m * 520 + koff + kt * 32 + q * 8);
            short8 bv = isconn
                ? ((const short8*)wpcn2)[(kt * 8 + job) * 64 + lane]
                : ((const short8*)wpep2)[(kt * 3 + (job - 8)) * 64 + lane];
            a2 = __builtin_amdgcn_mfma_f32_16x16x32_bf16(av, bv, a2, 0, 0, 0);
        }
        int c = (isconn ? job : (job - 8)) * 16 + m;
        float bb = isconn ? (c < 120 ? cn_b2[c] : 0.f) : (c < 36 ? ep_b2[c] : 0.f);
#pragma unroll
        for (int r = 0; r < 4; r++) {
            float v = 1.f / (1.f + __expf(-(a2[r] + bb)));
            int row = q * 4 + r;
            if (isconn) {
                if (c < 120) { s_conn[c * 17 + row] = v; s_rec0[c * 17 + row] = v; }
            } else {
                if (c < 36) s_ep[c * 17 + row] = v;
            }
        }
    }
    __syncthreads();

    const int row = tid >> 4, g = tid & 15;
    const int ns = G16_START[g];
    const int nodecnt = G16_START[g + 1] - ns;
    int ie[3][4], icnt[3], os[3], oc[3];
    float cr[3][4];
#pragma unroll
    for (int s = 0; s < 3; s++) {
        if (s < nodecnt) {
            int n = ns + s;
            icnt[s] = ADJC.cnt[n];
#pragma unroll
            for (int qx = 0; qx < 4; qx++) ie[s][qx] = ADJC.idx[n][qx];
            os[s] = ADJC.ostart[n];
            oc[s] = ADJC.ocnt[n];
#pragma unroll
            for (int oe = 0; oe < 4; oe++)
                cr[s][oe] = (oe < oc[s]) ? s_conn[(os[s] + oe) * 17 + row] : 0.f;
        } else {
            icnt[s] = 0; oc[s] = 0; os[s] = 0;
#pragma unroll
            for (int qx = 0; qx < 4; qx++) ie[s][qx] = 0;
#pragma unroll
            for (int oe = 0; oe < 4; oe++) cr[s][oe] = 0.f;
        }
    }
    float old0 = (g == 0) ? s_conn[0 * 17 + row] : 0.f;

    for (int it = 0; it < 36; it++) {
        const float* cur = (it & 1) ? s_rec1 : s_rec0;
        float* nxt = (it & 1) ? s_rec0 : s_rec1;
#pragma unroll
        for (int s = 0; s < 3; s++) {
            float sum = 0.f;
#pragma unroll
            for (int qx = 0; qx < 4; qx++)
                sum += (qx < icnt[s]) ? cur[ie[s][qx] * 17 + row] : 0.f;
            sum = fminf(sum, 1.f);
#pragma unroll
            for (int oe = 0; oe < 4; oe++) {
                if (oe < oc[s]) {
                    int e = os[s] + oe;
                    float nv = sum * cr[s][oe];
                    nxt[e * 17 + row] = nv;
                    if (g == 0 && s == 0 && oe == 0)
                        old0 = fminf(old0 + nv, 1.f);
                }
            }
        }
        __asm__ volatile("s_waitcnt lgkmcnt(0)" ::: "memory");
    }

    if (g == 0)
        out[b0 + row] = old0 * s_ep[0 * 17 + row] * s_ep[6 * 17 + row];
}

// ---------------------------------------------------------------------------
extern "C" void kernel_launch(void* const* d_in, const int* in_sizes, int n_in,
                              void* d_out, int out_size, void* d_ws, size_t ws_size,
                              hipStream_t stream) {
    const float* image = (const float*)d_in[0];
    const float* c1w = (const float*)d_in[1];
    const float* c1b = (const float*)d_in[2];
    const float* c2w = (const float*)d_in[3];
    const float* c2b = (const float*)d_in[4];
    const float* c3w = (const float*)d_in[5];
    const float* c3b = (const float*)d_in[6];
    const float* c4w = (const float*)d_in[7];
    const float* c4b = (const float*)d_in[8];
    const float* epw1 = (const float*)d_in[9];
    const float* epb1 = (const float*)d_in[10];
    const float* epw2 = (const float*)d_in[11];
    const float* epb2 = (const float*)d_in[12];
    const float* cnw1 = (const float*)d_in[13];
    const float* cnb1 = (const float*)d_in[14];
    const float* cnw2 = (const float*)d_in[15];
    const float* cnb2 = (const float*)d_in[16];

    const int B = in_sizes[0] / (32 * 32);  // 1024

    unsigned short* ws = (unsigned short*)d_ws;
    unsigned short* embo = ws;                            // B*256 bf16
    unsigned short* wp3 = embo + (size_t)B * 256;         // 51200
    unsigned short* wp4 = wp3 + 51200;                    // 102400
    unsigned short* wph1 = wp4 + 102400;                  // 131072
    unsigned short* wpcn2 = wph1 + 131072;                // 32768
    unsigned short* wpep2 = wpcn2 + 32768;                // 12288
    unsigned short* wpc = wpep2 + 12288;                  // 4096 (K=128)
    float* wcb = (float*)(wpc + 4096);                    // 32 f32

    k_prepall<<<1320, 256, 0, stream>>>(c1w, c1b, c2w, c2b, c3w, c4w,
                                        cnw1, epw1, cnw2, epw2,
                                        wpc, wcb, wp3, wp4, wph1, wpcn2, wpep2);
    k_convall<<<B / 2, 512, 0, stream>>>(image, wpc, wcb, wp3, c3b, wp4, c4b, embo);
    k_heads<<<B / 16, 256, 0, stream>>>(embo, wph1, cnb1, epb1,
                                        wpcn2, cnb2, wpep2, epb2, (float*)d_out);
}

// Round 6
// 142.784 us; speedup vs baseline: 1.1735x; 1.1321x over previous
//
#include <hip/hip_runtime.h>
#include <math.h>

typedef __attribute__((ext_vector_type(8))) short short8;
typedef __attribute__((ext_vector_type(4))) float float4v;
typedef __attribute__((ext_vector_type(4))) unsigned short ushort4v;

static __device__ __forceinline__ unsigned short f2bf(float f) {
    union { float f; unsigned u; } v; v.f = f;
    unsigned u = v.u;
    return (unsigned short)((u + 0x7fffu + ((u >> 16) & 1u)) >> 16);
}
static __device__ __forceinline__ unsigned pk2(float a, float b) {
    return (unsigned)f2bf(a) | ((unsigned)f2bf(b) << 16);
}

// ---------------------------------------------------------------------------
// Graph structure (compile-time), matching Python enumeration order.
// ---------------------------------------------------------------------------
struct AdjT {
    int src[120];
    int dst[120];
    int cnt[36];
    int idx[36][4];
    int ostart[36];
    int ocnt[36];
};

constexpr AdjT build_adj() {
    AdjT a{};
    const int ddx[4] = {-1, 0, 0, 1};
    const int ddy[4] = {0, -1, 1, 0};
    int ne = 0;
    for (int i = 0; i < 6; i++)
        for (int j = 0; j < 6; j++)
            for (int d = 0; d < 4; d++) {
                int x = i + ddx[d], y = j + ddy[d];
                if (x >= 0 && x < 6 && y >= 0 && y < 6) {
                    a.src[ne] = j * 6 + i;
                    a.dst[ne] = y * 6 + x;
                    ne++;
                }
            }
    for (int n = 0; n < 36; n++) {
        a.cnt[n] = 0;
        for (int e = 0; e < 120; e++)
            if (a.dst[e] == n) a.idx[n][a.cnt[n]++] = e;
    }
    for (int n = 0; n < 36; n++) { a.ostart[n] = 0; a.ocnt[n] = 0; }
    for (int e = 0; e < 120; e++) {
        a.ocnt[a.src[e]]++;
        if (e == 0 || a.src[e] != a.src[e - 1]) a.ostart[a.src[e]] = e;
    }
    return a;
}

__device__ constexpr AdjT ADJC = build_adj();

// ---------------------------------------------------------------------------
// K0: merged prep. Blocks 0..31: composite conv1∘conv2 weights, R19 K-layout:
// rows-of-12 -> t in [0,128): (ty,tx) = (t/12, t%12); valid ty<9 && tx<9,
// pad slots written 0 (NaN-safe). K=128, 4 K-steps.
// Blocks 32..1319: elementwise B-frag prep for conv3/conv4 + heads (as R15).
// ---------------------------------------------------------------------------
__global__ __launch_bounds__(256) void k_prepall(
    const float* __restrict__ w1, const float* __restrict__ b1,
    const float* __restrict__ w2, const float* __restrict__ b2,
    const float* __restrict__ w3, const float* __restrict__ w4,
    const float* __restrict__ cnw1, const float* __restrict__ epw1,
    const float* __restrict__ cnw2, const float* __restrict__ epw2,
    unsigned short* __restrict__ wpc, float* __restrict__ wcb,
    unsigned short* __restrict__ wp3, unsigned short* __restrict__ wp4,
    unsigned short* __restrict__ wph1, unsigned short* __restrict__ wpcn2,
    unsigned short* __restrict__ wpep2) {
    __shared__ float s_w1[800];
    __shared__ float s_w2[800];
    if (blockIdx.x < 32) {
        const int co = blockIdx.x, tid = threadIdx.x;
        for (int i = tid; i < 800; i += 256) {
            s_w1[i] = w1[i];
            s_w2[i] = w2[co * 800 + i];
        }
        __syncthreads();
        if (tid < 128) {
            int t = tid;
            int ty = t / 12, tx = t - 12 * ty;
            float val = 0.f;
            if (ty < 9 && tx < 9) {
                int ylo = ty > 4 ? ty - 4 : 0, yhi = ty < 4 ? ty : 4;
                int xlo = tx > 4 ? tx - 4 : 0, xhi = tx < 4 ? tx : 4;
                for (int k1y = ylo; k1y <= yhi; k1y++)
                    for (int k1x = xlo; k1x <= xhi; k1x++) {
                        int o1 = k1y * 5 + k1x;
                        int o2 = (ty - k1y) * 5 + (tx - k1x);
#pragma unroll
                        for (int ci = 0; ci < 32; ci++)
                            val += s_w1[ci * 25 + o1] * s_w2[ci * 25 + o2];
                    }
            }
            int n = co >> 1, nt = co & 1;
            int ks = t >> 5, r = t & 31, q = r >> 3, j = r & 7;
            wpc[ks * 1024 + nt * 512 + (q * 16 + n) * 8 + j] = f2bf(val);
        } else if (tid == 128) {
            float s = b2[co];
            for (int ci = 0; ci < 32; ci++) {
                float ws = 0.f;
#pragma unroll
                for (int t2 = 0; t2 < 25; t2++) ws += s_w2[ci * 25 + t2];
                s += b1[ci] * ws;
            }
            wcb[co] = s;
        }
        return;
    }
    int e = (blockIdx.x - 32) * 256 + threadIdx.x;
    if (e < 51200) {
        int j = e & 7, lane = (e >> 3) & 63, nt = (e >> 9) & 3, t = e >> 11;
        int co = 4 * (lane & 15) + nt, ci = (lane >> 4) * 8 + j;
        wp3[e] = f2bf(w3[(co * 32 + ci) * 25 + t]);
    } else if (e < 153600) {
        int e4 = e - 51200;
        int j = e4 & 7, lane = (e4 >> 3) & 63, nt = (e4 >> 9) & 3;
        int ks = (e4 >> 11) & 1, t = e4 >> 12;
        int co = 4 * (lane & 15) + nt, ci = ks * 32 + (lane >> 4) * 8 + j;
        wp4[e4] = f2bf(w4[(co * 64 + ci) * 25 + t]);
    } else {
        int eh = e - 153600;
        if (eh < 131072) {
            int j = eh & 7, lane = (eh >> 3) & 63, nt = (eh >> 9) & 31, kt = eh >> 14;
            int c = nt * 16 + (lane & 15);
            int k = kt * 32 + ((lane >> 4) << 3) + j;
            float v = (c < 256) ? cnw1[c * 256 + k] : epw1[(c - 256) * 256 + k];
            wph1[eh] = f2bf(v);
        } else if (eh < 163840) {
            int e2 = eh - 131072;
            int j = e2 & 7, lane = (e2 >> 3) & 63, nt = (e2 >> 9) & 7, kt = e2 >> 12;
            int c = nt * 16 + (lane & 15);
            int k = kt * 32 + ((lane >> 4) << 3) + j;
            wpcn2[e2] = f2bf(c < 120 ? cnw2[c * 256 + k] : 0.f);
        } else {
            int e3 = eh - 163840;
            int j = e3 & 7, lane = (e3 >> 3) & 63, idx = e3 >> 9;
            int kt = idx / 3, nt = idx - kt * 3;
            int c = nt * 16 + (lane & 15);
            int k = kt * 32 + ((lane >> 4) << 3) + j;
            wpep2[e3] = f2bf(c < 36 ? epw2[c * 256 + k] : 0.f);
        }
    }
}

// ---------------------------------------------------------------------------
// K_CONVALL (R19, unchanged): 2 img/block, 512 thr; composite A-reads via 4
// shifted image copies + rows-of-12 K=128 layout (8 ds_read_b64 per job).
// ---------------------------------------------------------------------------
#define REGSZ 10656
#define C3O 5760
#define CPY 1224

__global__ __launch_bounds__(512) void k_convall(
    const float* __restrict__ img,
    const unsigned short* __restrict__ wpc, const float* __restrict__ wcb,
    const unsigned short* __restrict__ wp3, const float* __restrict__ b3,
    const unsigned short* __restrict__ wp4, const float* __restrict__ b4,
    unsigned short* __restrict__ emb) {
    __shared__ __align__(16) unsigned short s_buf[2 * REGSZ];
    const int b2 = blockIdx.x, tid = threadIdx.x;
    const int lane = tid & 63, wave = tid >> 6;
    const int m = lane & 15, quad = lane >> 4;

    // ---- stage both images as 4 shifted bf16 copies (36-stride rows) ----
    {
        int simg = tid >> 8, t = tid & 255;
        float4 v = ((const float4*)(img + (size_t)(2 * b2 + simg) * 1024))[t];
        unsigned short pv[4];
        pv[0] = f2bf(v.x); pv[1] = f2bf(v.y);
        pv[2] = f2bf(v.z); pv[3] = f2bf(v.w);
        int r = t >> 3, x0 = (t & 7) * 4;
        int p36 = r * 36 + x0;
        unsigned short* reg = s_buf + simg * REGSZ + C3O;
#pragma unroll
        for (int c = 0; c < 4; c++)
#pragma unroll
            for (int i = 0; i < 4; i++) {
                int pos = p36 + i - c;
                if (pos >= 0) reg[c * CPY + pos] = pv[i];
            }
    }
    // zero-fill pad cols (x 32..35, r<32) + virtual rows 32..33 in all copies
    if (tid < 400) {
        int simg = tid >= 200, zz = tid - 200 * simg;
        int r, x;
        if (zz < 128) { r = zz >> 2; x = 32 + (zz & 3); }
        else { int rr = zz - 128; r = 32 + (rr >= 36 ? 1 : 0); x = rr - (rr >= 36 ? 36 : 0); }
        int p36 = r * 36 + x;
        unsigned short* reg = s_buf + simg * REGSZ + C3O;
#pragma unroll
        for (int c = 0; c < 4; c++) {
            int pos = p36 - c;
            if (pos >= 0 && pos < CPY) reg[c * CPY + pos] = 0;
        }
    }

    // composite-conv B-frags (4 K-steps, held in regs) + bias + A offsets
    const short8* wqc = (const short8*)wpc;
    short8 cb0[4], cb1[4];
#pragma unroll
    for (int ks = 0; ks < 4; ks++) {
        cb0[ks] = wqc[(ks * 2 + 0) * 64 + lane];
        cb1[ks] = wqc[(ks * 2 + 1) * 64 + lane];
    }
    const float bc0 = wcb[2 * m], bc1 = wcb[2 * m + 1];
    int ct1[4], ct2[4];
#pragma unroll
    for (int ks = 0; ks < 4; ks++) {
        int t0 = ks * 32 + quad * 8;
        ct1[ks] = (t0 / 12) * 36 + (t0 % 12);
        int t4 = t0 + 4;
        ct2[ks] = (t4 / 12) * 36 + (t4 % 12);
    }
    const short8* wq3 = (const short8*)wp3;

    __syncthreads();

    // ---- composite conv + in-register pool -> p2 [144][40] x 2 images ----
    for (int TT = wave; TT < 72; TT += 8) {
        int ci = TT >= 36 ? 1 : 0;
        int T = TT - 36 * ci;
        int pg = T * 4 + (m >> 2);            // pooled output index 0..143
        int py = (pg * 171) >> 11;            // == pg/12 for pg<144
        int px = pg - py * 12;
        int albase = (2 * py + ((m & 3) >> 1)) * 36 + 2 * px + (m & 1);
        const unsigned short* reg = s_buf + ci * REGSZ + C3O;
        float4v a0 = {0.f, 0.f, 0.f, 0.f};
        float4v a1 = {0.f, 0.f, 0.f, 0.f};
#pragma unroll
        for (int ks = 0; ks < 4; ks++) {
            int a = albase + ct1[ks];
            int c = a & 3;
            ushort4v lo = *(const ushort4v*)(reg + c * CPY + (a - c));
            a = albase + ct2[ks];
            c = a & 3;
            ushort4v hi = *(const ushort4v*)(reg + c * CPY + (a - c));
            short8 av;
            av[0] = (short)lo[0]; av[1] = (short)lo[1];
            av[2] = (short)lo[2]; av[3] = (short)lo[3];
            av[4] = (short)hi[0]; av[5] = (short)hi[1];
            av[6] = (short)hi[2]; av[7] = (short)hi[3];
            a0 = __builtin_amdgcn_mfma_f32_16x16x32_bf16(av, cb0[ks], a0, 0, 0, 0);
            a1 = __builtin_amdgcn_mfma_f32_16x16x32_bf16(av, cb1[ks], a1, 0, 0, 0);
        }
        float mx0 = fmaxf(fmaxf(a0[0], a0[1]), fmaxf(a0[2], a0[3])) + bc0;
        float mx1 = fmaxf(fmaxf(a1[0], a1[1]), fmaxf(a1[2], a1[3])) + bc1;
        int row = T * 4 + quad;
        *(unsigned*)(s_buf + ci * REGSZ + row * 40 + 2 * m) = pk2(mx0, mx1);
    }
    __syncthreads();

    // ---- conv3: wave = (img, Mtile-pair, Ntile-pair); 4 MFMA per tap ----
    {
        const int img3 = wave >> 2;
        const int mt0 = ((wave >> 1) & 1) * 2;
        const int nt0 = (wave & 1) * 2;
        const unsigned short* sb = s_buf + img3 * REGSZ;
        int a3[2];
#pragma unroll
        for (int mi = 0; mi < 2; mi++) {
            int pos3 = (mt0 + mi) * 16 + m;
            int y3 = pos3 >> 3, x3 = pos3 & 7;
            a3[mi] = (y3 * 12 + x3) * 40 + quad * 8;
        }
        float4v acc3[2][2];
#pragma unroll
        for (int mi = 0; mi < 2; mi++)
#pragma unroll
            for (int ni = 0; ni < 2; ni++)
                acc3[mi][ni] = (float4v){0.f, 0.f, 0.f, 0.f};
        short8 bw3[2];
        bw3[0] = wq3[nt0 * 64 + lane];
        bw3[1] = wq3[(nt0 + 1) * 64 + lane];
        for (int t = 0; t < 25; t++) {
            short8 nb3[2];
            if (t < 24) {
                nb3[0] = wq3[((t + 1) * 4 + nt0) * 64 + lane];
                nb3[1] = wq3[((t + 1) * 4 + nt0 + 1) * 64 + lane];
            }
            const int ky = t / 5, kx = t - ky * 5;
            const int toff = (ky * 12 + kx) * 40;
            short8 av0 = *(const short8*)(sb + a3[0] + toff);
            short8 av1 = *(const short8*)(sb + a3[1] + toff);
            acc3[0][0] = __builtin_amdgcn_mfma_f32_16x16x32_bf16(av0, bw3[0], acc3[0][0], 0, 0, 0);
            acc3[0][1] = __builtin_amdgcn_mfma_f32_16x16x32_bf16(av0, bw3[1], acc3[0][1], 0, 0, 0);
            acc3[1][0] = __builtin_amdgcn_mfma_f32_16x16x32_bf16(av1, bw3[0], acc3[1][0], 0, 0, 0);
            acc3[1][1] = __builtin_amdgcn_mfma_f32_16x16x32_bf16(av1, bw3[1], acc3[1][1], 0, 0, 0);
            if (t < 24) { bw3[0] = nb3[0]; bw3[1] = nb3[1]; }
        }
        float bb0 = b3[4 * m + nt0], bb1 = b3[4 * m + nt0 + 1];
#pragma unroll
        for (int mi = 0; mi < 2; mi++)
#pragma unroll
            for (int r = 0; r < 4; r++) {
                int row3 = (mt0 + mi) * 16 + quad * 4 + r;
                *(unsigned*)(s_buf + img3 * REGSZ + C3O + row3 * 72 + 4 * m + nt0) =
                    pk2(acc3[mi][0][r] + bb0, acc3[mi][1][r] + bb1);
            }
    }
    __syncthreads();

    // ---- conv4: wave = (img, Ntile); ALL 8 waves active ----
    {
        const int img4 = wave >> 2, nt4 = wave & 3;
        int y4 = m >> 2, x4 = m & 3;
        const unsigned short* sb = s_buf + img4 * REGSZ;
        int a4 = C3O + (y4 * 8 + x4) * 72 + quad * 8;
        float4v acc4 = (float4v){0.f, 0.f, 0.f, 0.f};
        const short8* wq4 = (const short8*)wp4;
        short8 cw0 = wq4[(0 * 4 + nt4) * 64 + lane];
        short8 cw1 = wq4[(1 * 4 + nt4) * 64 + lane];
        for (int t = 0; t < 25; t++) {
            short8 n0, n1;
            if (t < 24) {
                n0 = wq4[(((t + 1) * 2) * 4 + nt4) * 64 + lane];
                n1 = wq4[(((t + 1) * 2 + 1) * 4 + nt4) * 64 + lane];
            }
            const int ky = t / 5, kx = t - ky * 5;
            const int toff = (ky * 8 + kx) * 72;
            short8 av0 = *(const short8*)(sb + a4 + toff);
            acc4 = __builtin_amdgcn_mfma_f32_16x16x32_bf16(av0, cw0, acc4, 0, 0, 0);
            short8 av1 = *(const short8*)(sb + a4 + toff + 32);
            acc4 = __builtin_amdgcn_mfma_f32_16x16x32_bf16(av1, cw1, acc4, 0, 0, 0);
            if (t < 24) { cw0 = n0; cw1 = n1; }
        }
        float* s_c4 = (float*)(s_buf + img4 * REGSZ);
#pragma unroll
        for (int r = 0; r < 4; r++)
            s_c4[(quad * 4 + r) * 68 + 4 * m + nt4] = acc4[r];
    }
    __syncthreads();

    // emb epilogue: tid = img*256 + co*4 + pp; pool 2x2 + bias4 + flatten
    {
        const int simg = tid >> 8, t = tid & 255;
        const float* s_c4 = (const float*)(s_buf + simg * REGSZ);
        int co = t >> 2, pp = t & 3;
        int ppy = pp >> 1, ppx = pp & 1;
        float v0 = s_c4[((2 * ppy) * 4 + 2 * ppx) * 68 + co];
        float v1 = s_c4[((2 * ppy) * 4 + 2 * ppx + 1) * 68 + co];
        float v2 = s_c4[((2 * ppy + 1) * 4 + 2 * ppx) * 68 + co];
        float v3 = s_c4[((2 * ppy + 1) * 4 + 2 * ppx + 1) * 68 + co];
        emb[(size_t)(2 * b2 + simg) * 256 + t] =
            f2bf(fmaxf(fmaxf(v0, v1), fmaxf(v2, v3)) + b4[co]);
    }
}

// ---------------------------------------------------------------------------
// K5 (R20b): fused heads + recurrence. 1024 thr (16 waves) per block:
// phase1 GEMM 32 N-tiles over 16 waves (2 each); phase2 11 jobs 1/wave;
// phase3 node-state recurrence S'[n]=min(sum_{m->n} S[m]*conn[e],1) —
// one image per wave, one node per lane, pure register+shuffle (no LDS,
// no bank conflicts, no s_rec buffers). old0 via shfl(S,0) (pre-update).
// ---------------------------------------------------------------------------
__global__ __launch_bounds__(1024) void k_heads(
    const unsigned short* __restrict__ emb,
    const unsigned short* __restrict__ wph1,
    const float* __restrict__ cn_b1, const float* __restrict__ ep_b1,
    const unsigned short* __restrict__ wpcn2, const float* __restrict__ cn_b2,
    const unsigned short* __restrict__ wpep2, const float* __restrict__ ep_b2,
    float* __restrict__ out) {
    __shared__ unsigned short s_hid[16 * 520];
    __shared__ float s_conn[120 * 17];
    __shared__ float s_ep[36 * 17];
    const int tid = threadIdx.x;
    const int lane = tid & 63, wave = tid >> 6;
    const int m = lane & 15, q = lane >> 4;
    const int b0 = blockIdx.x * 16;

    // ---- phase 1: hid = relu(emb @ W1^T + b1), 512 cols over 16 waves ----
    float4v acc[2];
    acc[0] = (float4v){0.f, 0.f, 0.f, 0.f};
    acc[1] = (float4v){0.f, 0.f, 0.f, 0.f};
    const short8* wp1 = (const short8*)wph1;
    for (int kt = 0; kt < 8; kt++) {
        short8 av = *(const short8*)(emb + (size_t)(b0 + m) * 256 + kt * 32 + q * 8);
#pragma unroll
        for (int ntl = 0; ntl < 2; ntl++) {
            int nt = wave * 2 + ntl;
            short8 bv = wp1[(kt * 32 + nt) * 64 + lane];
            acc[ntl] = __builtin_amdgcn_mfma_f32_16x16x32_bf16(av, bv, acc[ntl], 0, 0, 0);
        }
    }
#pragma unroll
    for (int ntl = 0; ntl < 2; ntl++) {
        int c = (wave * 2 + ntl) * 16 + m;
        float bb = (c < 256) ? cn_b1[c] : ep_b1[c - 256];
#pragma unroll
        for (int r = 0; r < 4; r++)
            s_hid[(q * 4 + r) * 520 + c] = f2bf(fmaxf(acc[ntl][r] + bb, 0.f));
    }
    __syncthreads();

    // ---- phase 2: conn (8 jobs) + ep (3 jobs), one job per wave ----
    if (wave < 11) {
        const int job = wave;
        const bool isconn = job < 8;
        const int koff = isconn ? 0 : 256;
        float4v a2 = (float4v){0.f, 0.f, 0.f, 0.f};
        for (int kt = 0; kt < 8; kt++) {
            short8 av = *(const short8*)(s_hid + m * 520 + koff + kt * 32 + q * 8);
            short8 bv = isconn
                ? ((const short8*)wpcn2)[(kt * 8 + job) * 64 + lane]
                : ((const short8*)wpep2)[(kt * 3 + (job - 8)) * 64 + lane];
            a2 = __builtin_amdgcn_mfma_f32_16x16x32_bf16(av, bv, a2, 0, 0, 0);
        }
        int c = (isconn ? job : (job - 8)) * 16 + m;
        float bb = isconn ? (c < 120 ? cn_b2[c] : 0.f) : (c < 36 ? ep_b2[c] : 0.f);
#pragma unroll
        for (int r = 0; r < 4; r++) {
            float v = 1.f / (1.f + __expf(-(a2[r] + bb)));
            int row = q * 4 + r;
            if (isconn) {
                if (c < 120) s_conn[c * 17 + row] = v;
            } else {
                if (c < 36) s_ep[c * 17 + row] = v;
            }
        }
    }
    __syncthreads();

    // ---- phase 3: register/shuffle node-state recurrence, img = wave ----
    {
        const int w = wave;          // image index within block
        const int n = lane;          // node index (active n < 36)
        int msrc[4];
        float cr[4];
        const int cnt = (n < 36) ? ADJC.cnt[n] : 0;
#pragma unroll
        for (int k = 0; k < 4; k++) {
            if (n < 36 && k < cnt) {
                int e = ADJC.idx[n][k];
                msrc[k] = ADJC.src[e];
                cr[k] = s_conn[e * 17 + w];
            } else {
                msrc[k] = 0;
                cr[k] = 0.f;
            }
        }
        float S = fminf(cr[0] + cr[1] + cr[2] + cr[3], 1.f);
        const float conn0 = s_conn[0 * 17 + w];
        float old0 = conn0;
        for (int it = 0; it < 36; it++) {
            float s0 = __shfl(S, 0);
            float g0 = __shfl(S, msrc[0]);
            float g1 = __shfl(S, msrc[1]);
            float g2 = __shfl(S, msrc[2]);
            float g3 = __shfl(S, msrc[3]);
            old0 = fminf(old0 + s0 * conn0, 1.f);
            S = fminf(g0 * cr[0] + g1 * cr[1] + g2 * cr[2] + g3 * cr[3], 1.f);
        }
        if (lane == 0)
            out[b0 + w] = old0 * s_ep[0 * 17 + w] * s_ep[6 * 17 + w];
    }
}

// ---------------------------------------------------------------------------
extern "C" void kernel_launch(void* const* d_in, const int* in_sizes, int n_in,
                              void* d_out, int out_size, void* d_ws, size_t ws_size,
                              hipStream_t stream) {
    const float* image = (const float*)d_in[0];
    const float* c1w = (const float*)d_in[1];
    const float* c1b = (const float*)d_in[2];
    const float* c2w = (const float*)d_in[3];
    const float* c2b = (const float*)d_in[4];
    const float* c3w = (const float*)d_in[5];
    const float* c3b = (const float*)d_in[6];
    const float* c4w = (const float*)d_in[7];
    const float* c4b = (const float*)d_in[8];
    const float* epw1 = (const float*)d_in[9];
    const float* epb1 = (const float*)d_in[10];
    const float* epw2 = (const float*)d_in[11];
    const float* epb2 = (const float*)d_in[12];
    const float* cnw1 = (const float*)d_in[13];
    const float* cnb1 = (const float*)d_in[14];
    const float* cnw2 = (const float*)d_in[15];
    const float* cnb2 = (const float*)d_in[16];

    const int B = in_sizes[0] / (32 * 32);  // 1024

    unsigned short* ws = (unsigned short*)d_ws;
    unsigned short* embo = ws;                            // B*256 bf16
    unsigned short* wp3 = embo + (size_t)B * 256;         // 51200
    unsigned short* wp4 = wp3 + 51200;                    // 102400
    unsigned short* wph1 = wp4 + 102400;                  // 131072
    unsigned short* wpcn2 = wph1 + 131072;                // 32768
    unsigned short* wpep2 = wpcn2 + 32768;                // 12288
    unsigned short* wpc = wpep2 + 12288;                  // 4096 (K=128)
    float* wcb = (float*)(wpc + 4096);                    // 32 f32

    k_prepall<<<1320, 256, 0, stream>>>(c1w, c1b, c2w, c2b, c3w, c4w,
                                        cnw1, epw1, cnw2, epw2,
                                        wpc, wcb, wp3, wp4, wph1, wpcn2, wpep2);
    k_convall<<<B / 2, 512, 0, stream>>>(image, wpc, wcb, wp3, c3b, wp4, c4b, embo);
    k_heads<<<B / 16, 1024, 0, stream>>>(embo, wph1, cnb1, epb1,
                                         wpcn2, cnb2, wpep2, epb2, (float*)d_out);
}

// Round 7
// 137.170 us; speedup vs baseline: 1.2215x; 1.0409x over previous
//
#include <hip/hip_runtime.h>
#include <math.h>

typedef __attribute__((ext_vector_type(8))) short short8;
typedef __attribute__((ext_vector_type(4))) float float4v;
typedef __attribute__((ext_vector_type(4))) unsigned short ushort4v;

static __device__ __forceinline__ unsigned short f2bf(float f) {
    union { float f; unsigned u; } v; v.f = f;
    unsigned u = v.u;
    return (unsigned short)((u + 0x7fffu + ((u >> 16) & 1u)) >> 16);
}
static __device__ __forceinline__ unsigned pk2(float a, float b) {
    return (unsigned)f2bf(a) | ((unsigned)f2bf(b) << 16);
}

// ---------------------------------------------------------------------------
// Graph structure (compile-time), matching Python enumeration order.
// ---------------------------------------------------------------------------
struct AdjT {
    int src[120];
    int dst[120];
    int cnt[36];
    int idx[36][4];
    int ostart[36];
    int ocnt[36];
};

constexpr AdjT build_adj() {
    AdjT a{};
    const int ddx[4] = {-1, 0, 0, 1};
    const int ddy[4] = {0, -1, 1, 0};
    int ne = 0;
    for (int i = 0; i < 6; i++)
        for (int j = 0; j < 6; j++)
            for (int d = 0; d < 4; d++) {
                int x = i + ddx[d], y = j + ddy[d];
                if (x >= 0 && x < 6 && y >= 0 && y < 6) {
                    a.src[ne] = j * 6 + i;
                    a.dst[ne] = y * 6 + x;
                    ne++;
                }
            }
    for (int n = 0; n < 36; n++) {
        a.cnt[n] = 0;
        for (int e = 0; e < 120; e++)
            if (a.dst[e] == n) a.idx[n][a.cnt[n]++] = e;
    }
    for (int n = 0; n < 36; n++) { a.ostart[n] = 0; a.ocnt[n] = 0; }
    for (int e = 0; e < 120; e++) {
        a.ocnt[a.src[e]]++;
        if (e == 0 || a.src[e] != a.src[e - 1]) a.ostart[a.src[e]] = e;
    }
    return a;
}

__device__ constexpr AdjT ADJC = build_adj();

// ---------------------------------------------------------------------------
// K0: merged prep. Blocks 0..31 (R21): composite conv1∘conv2 weights via
// REGISTER outer-product: lane=ci holds w1[ci][0..24]+w2[co][ci][0..24] in
// regs; 625 statically-indexed FMAs into acc[81]; shfl_xor butterfly over 32
// ci-lanes; predicated stores in R19 rows-of-12 K=128 layout (pads 0).
// Replaces ~1600 LDS reads/thread serial loop (was the composite-block cost).
// Blocks 32..1319: elementwise B-frag prep (unchanged).
// ---------------------------------------------------------------------------
__global__ __launch_bounds__(256) void k_prepall(
    const float* __restrict__ w1, const float* __restrict__ b1,
    const float* __restrict__ w2, const float* __restrict__ b2,
    const float* __restrict__ w3, const float* __restrict__ w4,
    const float* __restrict__ cnw1, const float* __restrict__ epw1,
    const float* __restrict__ cnw2, const float* __restrict__ epw2,
    unsigned short* __restrict__ wpc, float* __restrict__ wcb,
    unsigned short* __restrict__ wp3, unsigned short* __restrict__ wp4,
    unsigned short* __restrict__ wph1, unsigned short* __restrict__ wpcn2,
    unsigned short* __restrict__ wpep2) {
    __shared__ float s_w1[800];
    __shared__ float s_w2[800];
    if (blockIdx.x < 32) {
        const int co = blockIdx.x, tid = threadIdx.x;
        for (int i = tid; i < 800; i += 256) {
            s_w1[i] = w1[i];
            s_w2[i] = w2[co * 800 + i];
        }
        __syncthreads();
        if (tid < 64) {
            const int ci = tid & 31;   // lanes 32-63 duplicate ci (harmless)
            float w1r[25], w2r[25];
#pragma unroll
            for (int o = 0; o < 25; o++) {
                w1r[o] = s_w1[ci * 25 + o];
                w2r[o] = s_w2[ci * 25 + o];
            }
            float acc[81];
#pragma unroll
            for (int i = 0; i < 81; i++) acc[i] = 0.f;
#pragma unroll
            for (int k1y = 0; k1y < 5; k1y++)
#pragma unroll
                for (int k1x = 0; k1x < 5; k1x++)
#pragma unroll
                    for (int k2y = 0; k2y < 5; k2y++)
#pragma unroll
                        for (int k2x = 0; k2x < 5; k2x++)
                            acc[(k1y + k2y) * 9 + (k1x + k2x)] +=
                                w1r[k1y * 5 + k1x] * w2r[k2y * 5 + k2x];
            // butterfly reduce over the 32 ci-lanes (offsets<32 stay in-group)
#pragma unroll
            for (int i = 0; i < 81; i++) {
                float v = acc[i];
                v += __shfl_xor(v, 1);
                v += __shfl_xor(v, 2);
                v += __shfl_xor(v, 4);
                v += __shfl_xor(v, 8);
                v += __shfl_xor(v, 16);
                acc[i] = v;
            }
            const int n = co >> 1, nt = co & 1;
#pragma unroll
            for (int t = 0; t < 128; t++) {
                const int ty = t / 12, tx = t - 12 * (t / 12);
                float val = (ty < 9 && tx < 9) ? acc[ty * 9 + tx] : 0.f;
                if ((tid & 63) == (t & 63)) {
                    int ks = t >> 5, r = t & 31, q = r >> 3, j = r & 7;
                    wpc[ks * 1024 + nt * 512 + (q * 16 + n) * 8 + j] = f2bf(val);
                }
            }
            // bias: wcb[co] = b2[co] + sum_ci b1[ci] * sum_t w2[co][ci][t]
            float sw = 0.f;
#pragma unroll
            for (int o = 0; o < 25; o++) sw += w2r[o];
            float pb = b1[ci] * sw;
            pb += __shfl_xor(pb, 1);
            pb += __shfl_xor(pb, 2);
            pb += __shfl_xor(pb, 4);
            pb += __shfl_xor(pb, 8);
            pb += __shfl_xor(pb, 16);
            if (tid == 0) wcb[co] = b2[co] + pb;
        }
        return;
    }
    int e = (blockIdx.x - 32) * 256 + threadIdx.x;
    if (e < 51200) {
        int j = e & 7, lane = (e >> 3) & 63, nt = (e >> 9) & 3, t = e >> 11;
        int co = 4 * (lane & 15) + nt, ci = (lane >> 4) * 8 + j;
        wp3[e] = f2bf(w3[(co * 32 + ci) * 25 + t]);
    } else if (e < 153600) {
        int e4 = e - 51200;
        int j = e4 & 7, lane = (e4 >> 3) & 63, nt = (e4 >> 9) & 3;
        int ks = (e4 >> 11) & 1, t = e4 >> 12;
        int co = 4 * (lane & 15) + nt, ci = ks * 32 + (lane >> 4) * 8 + j;
        wp4[e4] = f2bf(w4[(co * 64 + ci) * 25 + t]);
    } else {
        int eh = e - 153600;
        if (eh < 131072) {
            int j = eh & 7, lane = (eh >> 3) & 63, nt = (eh >> 9) & 31, kt = eh >> 14;
            int c = nt * 16 + (lane & 15);
            int k = kt * 32 + ((lane >> 4) << 3) + j;
            float v = (c < 256) ? cnw1[c * 256 + k] : epw1[(c - 256) * 256 + k];
            wph1[eh] = f2bf(v);
        } else if (eh < 163840) {
            int e2 = eh - 131072;
            int j = e2 & 7, lane = (e2 >> 3) & 63, nt = (e2 >> 9) & 7, kt = e2 >> 12;
            int c = nt * 16 + (lane & 15);
            int k = kt * 32 + ((lane >> 4) << 3) + j;
            wpcn2[e2] = f2bf(c < 120 ? cnw2[c * 256 + k] : 0.f);
        } else {
            int e3 = eh - 163840;
            int j = e3 & 7, lane = (e3 >> 3) & 63, idx = e3 >> 9;
            int kt = idx / 3, nt = idx - kt * 3;
            int c = nt * 16 + (lane & 15);
            int k = kt * 32 + ((lane >> 4) << 3) + j;
            wpep2[e3] = f2bf(c < 36 ? epw2[c * 256 + k] : 0.f);
        }
    }
}

// ---------------------------------------------------------------------------
// K_CONVALL (R21): R19 structure + 2-deep B-prefetch in conv3/conv4 (covers
// ~250cy L2 latency; 1-deep left each tap exposed). Everything else as R19.
// ---------------------------------------------------------------------------
#define REGSZ 10656
#define C3O 5760
#define CPY 1224

__global__ __launch_bounds__(512) void k_convall(
    const float* __restrict__ img,
    const unsigned short* __restrict__ wpc, const float* __restrict__ wcb,
    const unsigned short* __restrict__ wp3, const float* __restrict__ b3,
    const unsigned short* __restrict__ wp4, const float* __restrict__ b4,
    unsigned short* __restrict__ emb) {
    __shared__ __align__(16) unsigned short s_buf[2 * REGSZ];
    const int b2 = blockIdx.x, tid = threadIdx.x;
    const int lane = tid & 63, wave = tid >> 6;
    const int m = lane & 15, quad = lane >> 4;

    // ---- stage both images as 4 shifted bf16 copies (36-stride rows) ----
    {
        int simg = tid >> 8, t = tid & 255;
        float4 v = ((const float4*)(img + (size_t)(2 * b2 + simg) * 1024))[t];
        unsigned short pv[4];
        pv[0] = f2bf(v.x); pv[1] = f2bf(v.y);
        pv[2] = f2bf(v.z); pv[3] = f2bf(v.w);
        int r = t >> 3, x0 = (t & 7) * 4;
        int p36 = r * 36 + x0;
        unsigned short* reg = s_buf + simg * REGSZ + C3O;
#pragma unroll
        for (int c = 0; c < 4; c++)
#pragma unroll
            for (int i = 0; i < 4; i++) {
                int pos = p36 + i - c;
                if (pos >= 0) reg[c * CPY + pos] = pv[i];
            }
    }
    // zero-fill pad cols (x 32..35, r<32) + virtual rows 32..33 in all copies
    if (tid < 400) {
        int simg = tid >= 200, zz = tid - 200 * simg;
        int r, x;
        if (zz < 128) { r = zz >> 2; x = 32 + (zz & 3); }
        else { int rr = zz - 128; r = 32 + (rr >= 36 ? 1 : 0); x = rr - (rr >= 36 ? 36 : 0); }
        int p36 = r * 36 + x;
        unsigned short* reg = s_buf + simg * REGSZ + C3O;
#pragma unroll
        for (int c = 0; c < 4; c++) {
            int pos = p36 - c;
            if (pos >= 0 && pos < CPY) reg[c * CPY + pos] = 0;
        }
    }

    // composite-conv B-frags (4 K-steps, held in regs) + bias + A offsets
    const short8* wqc = (const short8*)wpc;
    short8 cb0[4], cb1[4];
#pragma unroll
    for (int ks = 0; ks < 4; ks++) {
        cb0[ks] = wqc[(ks * 2 + 0) * 64 + lane];
        cb1[ks] = wqc[(ks * 2 + 1) * 64 + lane];
    }
    const float bc0 = wcb[2 * m], bc1 = wcb[2 * m + 1];
    int ct1[4], ct2[4];
#pragma unroll
    for (int ks = 0; ks < 4; ks++) {
        int t0 = ks * 32 + quad * 8;
        ct1[ks] = (t0 / 12) * 36 + (t0 % 12);
        int t4 = t0 + 4;
        ct2[ks] = (t4 / 12) * 36 + (t4 % 12);
    }
    const short8* wq3 = (const short8*)wp3;

    __syncthreads();

    // ---- composite conv + in-register pool -> p2 [144][40] x 2 images ----
    for (int TT = wave; TT < 72; TT += 8) {
        int ci = TT >= 36 ? 1 : 0;
        int T = TT - 36 * ci;
        int pg = T * 4 + (m >> 2);            // pooled output index 0..143
        int py = (pg * 171) >> 11;            // == pg/12 for pg<144
        int px = pg - py * 12;
        int albase = (2 * py + ((m & 3) >> 1)) * 36 + 2 * px + (m & 1);
        const unsigned short* reg = s_buf + ci * REGSZ + C3O;
        float4v a0 = {0.f, 0.f, 0.f, 0.f};
        float4v a1 = {0.f, 0.f, 0.f, 0.f};
#pragma unroll
        for (int ks = 0; ks < 4; ks++) {
            int a = albase + ct1[ks];
            int c = a & 3;
            ushort4v lo = *(const ushort4v*)(reg + c * CPY + (a - c));
            a = albase + ct2[ks];
            c = a & 3;
            ushort4v hi = *(const ushort4v*)(reg + c * CPY + (a - c));
            short8 av;
            av[0] = (short)lo[0]; av[1] = (short)lo[1];
            av[2] = (short)lo[2]; av[3] = (short)lo[3];
            av[4] = (short)hi[0]; av[5] = (short)hi[1];
            av[6] = (short)hi[2]; av[7] = (short)hi[3];
            a0 = __builtin_amdgcn_mfma_f32_16x16x32_bf16(av, cb0[ks], a0, 0, 0, 0);
            a1 = __builtin_amdgcn_mfma_f32_16x16x32_bf16(av, cb1[ks], a1, 0, 0, 0);
        }
        float mx0 = fmaxf(fmaxf(a0[0], a0[1]), fmaxf(a0[2], a0[3])) + bc0;
        float mx1 = fmaxf(fmaxf(a1[0], a1[1]), fmaxf(a1[2], a1[3])) + bc1;
        int row = T * 4 + quad;
        *(unsigned*)(s_buf + ci * REGSZ + row * 40 + 2 * m) = pk2(mx0, mx1);
    }
    __syncthreads();

    // ---- conv3: wave = (img, Mtile-pair, Ntile-pair); 2-deep B-prefetch ----
    {
        const int img3 = wave >> 2;
        const int mt0 = ((wave >> 1) & 1) * 2;
        const int nt0 = (wave & 1) * 2;
        const unsigned short* sb = s_buf + img3 * REGSZ;
        int a3[2];
#pragma unroll
        for (int mi = 0; mi < 2; mi++) {
            int pos3 = (mt0 + mi) * 16 + m;
            int y3 = pos3 >> 3, x3 = pos3 & 7;
            a3[mi] = (y3 * 12 + x3) * 40 + quad * 8;
        }
        float4v acc3[2][2];
#pragma unroll
        for (int mi = 0; mi < 2; mi++)
#pragma unroll
            for (int ni = 0; ni < 2; ni++)
                acc3[mi][ni] = (float4v){0.f, 0.f, 0.f, 0.f};
        short8 bA0 = wq3[(0 * 4 + nt0) * 64 + lane];
        short8 bA1 = wq3[(0 * 4 + nt0 + 1) * 64 + lane];
        short8 bB0 = wq3[(1 * 4 + nt0) * 64 + lane];
        short8 bB1 = wq3[(1 * 4 + nt0 + 1) * 64 + lane];
        for (int t = 0; t < 25; t++) {
            short8 bC0, bC1;
            if (t < 23) {
                bC0 = wq3[((t + 2) * 4 + nt0) * 64 + lane];
                bC1 = wq3[((t + 2) * 4 + nt0 + 1) * 64 + lane];
            }
            const int ky = t / 5, kx = t - ky * 5;
            const int toff = (ky * 12 + kx) * 40;
            short8 av0 = *(const short8*)(sb + a3[0] + toff);
            short8 av1 = *(const short8*)(sb + a3[1] + toff);
            acc3[0][0] = __builtin_amdgcn_mfma_f32_16x16x32_bf16(av0, bA0, acc3[0][0], 0, 0, 0);
            acc3[0][1] = __builtin_amdgcn_mfma_f32_16x16x32_bf16(av0, bA1, acc3[0][1], 0, 0, 0);
            acc3[1][0] = __builtin_amdgcn_mfma_f32_16x16x32_bf16(av1, bA0, acc3[1][0], 0, 0, 0);
            acc3[1][1] = __builtin_amdgcn_mfma_f32_16x16x32_bf16(av1, bA1, acc3[1][1], 0, 0, 0);
            bA0 = bB0; bA1 = bB1;
            if (t < 23) { bB0 = bC0; bB1 = bC1; }
        }
        float bb0 = b3[4 * m + nt0], bb1 = b3[4 * m + nt0 + 1];
#pragma unroll
        for (int mi = 0; mi < 2; mi++)
#pragma unroll
            for (int r = 0; r < 4; r++) {
                int row3 = (mt0 + mi) * 16 + quad * 4 + r;
                *(unsigned*)(s_buf + img3 * REGSZ + C3O + row3 * 72 + 4 * m + nt0) =
                    pk2(acc3[mi][0][r] + bb0, acc3[mi][1][r] + bb1);
            }
    }
    __syncthreads();

    // ---- conv4: wave = (img, Ntile); 2-deep B-prefetch ----
    {
        const int img4 = wave >> 2, nt4 = wave & 3;
        int y4 = m >> 2, x4 = m & 3;
        const unsigned short* sb = s_buf + img4 * REGSZ;
        int a4 = C3O + (y4 * 8 + x4) * 72 + quad * 8;
        float4v acc4 = (float4v){0.f, 0.f, 0.f, 0.f};
        const short8* wq4 = (const short8*)wp4;
        short8 cA0 = wq4[((0 * 2 + 0) * 4 + nt4) * 64 + lane];
        short8 cA1 = wq4[((0 * 2 + 1) * 4 + nt4) * 64 + lane];
        short8 cB0 = wq4[((1 * 2 + 0) * 4 + nt4) * 64 + lane];
        short8 cB1 = wq4[((1 * 2 + 1) * 4 + nt4) * 64 + lane];
        for (int t = 0; t < 25; t++) {
            short8 cC0, cC1;
            if (t < 23) {
                cC0 = wq4[(((t + 2) * 2 + 0) * 4 + nt4) * 64 + lane];
                cC1 = wq4[(((t + 2) * 2 + 1) * 4 + nt4) * 64 + lane];
            }
            const int ky = t / 5, kx = t - ky * 5;
            const int toff = (ky * 8 + kx) * 72;
            short8 av0 = *(const short8*)(sb + a4 + toff);
            acc4 = __builtin_amdgcn_mfma_f32_16x16x32_bf16(av0, cA0, acc4, 0, 0, 0);
            short8 av1 = *(const short8*)(sb + a4 + toff + 32);
            acc4 = __builtin_amdgcn_mfma_f32_16x16x32_bf16(av1, cA1, acc4, 0, 0, 0);
            cA0 = cB0; cA1 = cB1;
            if (t < 23) { cB0 = cC0; cB1 = cC1; }
        }
        float* s_c4 = (float*)(s_buf + img4 * REGSZ);
#pragma unroll
        for (int r = 0; r < 4; r++)
            s_c4[(quad * 4 + r) * 68 + 4 * m + nt4] = acc4[r];
    }
    __syncthreads();

    // emb epilogue: tid = img*256 + co*4 + pp; pool 2x2 + bias4 + flatten
    {
        const int simg = tid >> 8, t = tid & 255;
        const float* s_c4 = (const float*)(s_buf + simg * REGSZ);
        int co = t >> 2, pp = t & 3;
        int ppy = pp >> 1, ppx = pp & 1;
        float v0 = s_c4[((2 * ppy) * 4 + 2 * ppx) * 68 + co];
        float v1 = s_c4[((2 * ppy) * 4 + 2 * ppx + 1) * 68 + co];
        float v2 = s_c4[((2 * ppy + 1) * 4 + 2 * ppx) * 68 + co];
        float v3 = s_c4[((2 * ppy + 1) * 4 + 2 * ppx + 1) * 68 + co];
        emb[(size_t)(2 * b2 + simg) * 256 + t] =
            f2bf(fmaxf(fmaxf(v0, v1), fmaxf(v2, v3)) + b4[co]);
    }
}

// ---------------------------------------------------------------------------
// K5 (R20b, unchanged): fused heads + register/shuffle recurrence.
// ---------------------------------------------------------------------------
__global__ __launch_bounds__(1024) void k_heads(
    const unsigned short* __restrict__ emb,
    const unsigned short* __restrict__ wph1,
    const float* __restrict__ cn_b1, const float* __restrict__ ep_b1,
    const unsigned short* __restrict__ wpcn2, const float* __restrict__ cn_b2,
    const unsigned short* __restrict__ wpep2, const float* __restrict__ ep_b2,
    float* __restrict__ out) {
    __shared__ unsigned short s_hid[16 * 520];
    __shared__ float s_conn[120 * 17];
    __shared__ float s_ep[36 * 17];
    const int tid = threadIdx.x;
    const int lane = tid & 63, wave = tid >> 6;
    const int m = lane & 15, q = lane >> 4;
    const int b0 = blockIdx.x * 16;

    // ---- phase 1: hid = relu(emb @ W1^T + b1), 512 cols over 16 waves ----
    float4v acc[2];
    acc[0] = (float4v){0.f, 0.f, 0.f, 0.f};
    acc[1] = (float4v){0.f, 0.f, 0.f, 0.f};
    const short8* wp1 = (const short8*)wph1;
    for (int kt = 0; kt < 8; kt++) {
        short8 av = *(const short8*)(emb + (size_t)(b0 + m) * 256 + kt * 32 + q * 8);
#pragma unroll
        for (int ntl = 0; ntl < 2; ntl++) {
            int nt = wave * 2 + ntl;
            short8 bv = wp1[(kt * 32 + nt) * 64 + lane];
            acc[ntl] = __builtin_amdgcn_mfma_f32_16x16x32_bf16(av, bv, acc[ntl], 0, 0, 0);
        }
    }
#pragma unroll
    for (int ntl = 0; ntl < 2; ntl++) {
        int c = (wave * 2 + ntl) * 16 + m;
        float bb = (c < 256) ? cn_b1[c] : ep_b1[c - 256];
#pragma unroll
        for (int r = 0; r < 4; r++)
            s_hid[(q * 4 + r) * 520 + c] = f2bf(fmaxf(acc[ntl][r] + bb, 0.f));
    }
    __syncthreads();

    // ---- phase 2: conn (8 jobs) + ep (3 jobs), one job per wave ----
    if (wave < 11) {
        const int job = wave;
        const bool isconn = job < 8;
        const int koff = isconn ? 0 : 256;
        float4v a2 = (float4v){0.f, 0.f, 0.f, 0.f};
        for (int kt = 0; kt < 8; kt++) {
            short8 av = *(const short8*)(s_hid + m * 520 + koff + kt * 32 + q * 8);
            short8 bv = isconn
                ? ((const short8*)wpcn2)[(kt * 8 + job) * 64 + lane]
                : ((const short8*)wpep2)[(kt * 3 + (job - 8)) * 64 + lane];
            a2 = __builtin_amdgcn_mfma_f32_16x16x32_bf16(av, bv, a2, 0, 0, 0);
        }
        int c = (isconn ? job : (job - 8)) * 16 + m;
        float bb = isconn ? (c < 120 ? cn_b2[c] : 0.f) : (c < 36 ? ep_b2[c] : 0.f);
#pragma unroll
        for (int r = 0; r < 4; r++) {
            float v = 1.f / (1.f + __expf(-(a2[r] + bb)));
            int row = q * 4 + r;
            if (isconn) {
                if (c < 120) s_conn[c * 17 + row] = v;
            } else {
                if (c < 36) s_ep[c * 17 + row] = v;
            }
        }
    }
    __syncthreads();

    // ---- phase 3: register/shuffle node-state recurrence, img = wave ----
    {
        const int w = wave;          // image index within block
        const int n = lane;          // node index (active n < 36)
        int msrc[4];
        float cr[4];
        const int cnt = (n < 36) ? ADJC.cnt[n] : 0;
#pragma unroll
        for (int k = 0; k < 4; k++) {
            if (n < 36 && k < cnt) {
                int e = ADJC.idx[n][k];
                msrc[k] = ADJC.src[e];
                cr[k] = s_conn[e * 17 + w];
            } else {
                msrc[k] = 0;
                cr[k] = 0.f;
            }
        }
        float S = fminf(cr[0] + cr[1] + cr[2] + cr[3], 1.f);
        const float conn0 = s_conn[0 * 17 + w];
        float old0 = conn0;
        for (int it = 0; it < 36; it++) {
            float s0 = __shfl(S, 0);
            float g0 = __shfl(S, msrc[0]);
            float g1 = __shfl(S, msrc[1]);
            float g2 = __shfl(S, msrc[2]);
            float g3 = __shfl(S, msrc[3]);
            old0 = fminf(old0 + s0 * conn0, 1.f);
            S = fminf(g0 * cr[0] + g1 * cr[1] + g2 * cr[2] + g3 * cr[3], 1.f);
        }
        if (lane == 0)
            out[b0 + w] = old0 * s_ep[0 * 17 + w] * s_ep[6 * 17 + w];
    }
}

// ---------------------------------------------------------------------------
extern "C" void kernel_launch(void* const* d_in, const int* in_sizes, int n_in,
                              void* d_out, int out_size, void* d_ws, size_t ws_size,
                              hipStream_t stream) {
    const float* image = (const float*)d_in[0];
    const float* c1w = (const float*)d_in[1];
    const float* c1b = (const float*)d_in[2];
    const float* c2w = (const float*)d_in[3];
    const float* c2b = (const float*)d_in[4];
    const float* c3w = (const float*)d_in[5];
    const float* c3b = (const float*)d_in[6];
    const float* c4w = (const float*)d_in[7];
    const float* c4b = (const float*)d_in[8];
    const float* epw1 = (const float*)d_in[9];
    const float* epb1 = (const float*)d_in[10];
    const float* epw2 = (const float*)d_in[11];
    const float* epb2 = (const float*)d_in[12];
    const float* cnw1 = (const float*)d_in[13];
    const float* cnb1 = (const float*)d_in[14];
    const float* cnw2 = (const float*)d_in[15];
    const float* cnb2 = (const float*)d_in[16];

    const int B = in_sizes[0] / (32 * 32);  // 1024

    unsigned short* ws = (unsigned short*)d_ws;
    unsigned short* embo = ws;                            // B*256 bf16
    unsigned short* wp3 = embo + (size_t)B * 256;         // 51200
    unsigned short* wp4 = wp3 + 51200;                    // 102400
    unsigned short* wph1 = wp4 + 102400;                  // 131072
    unsigned short* wpcn2 = wph1 + 131072;                // 32768
    unsigned short* wpep2 = wpcn2 + 32768;                // 12288
    unsigned short* wpc = wpep2 + 12288;                  // 4096 (K=128)
    float* wcb = (float*)(wpc + 4096);                    // 32 f32

    k_prepall<<<1320, 256, 0, stream>>>(c1w, c1b, c2w, c2b, c3w, c4w,
                                        cnw1, epw1, cnw2, epw2,
                                        wpc, wcb, wp3, wp4, wph1, wpcn2, wpep2);
    k_convall<<<B / 2, 512, 0, stream>>>(image, wpc, wcb, wp3, c3b, wp4, c4b, embo);
    k_heads<<<B / 16, 1024, 0, stream>>>(embo, wph1, cnb1, epb1,
                                         wpcn2, cnb2, wpep2, epb2, (float*)d_out);
}

// Round 8
// 132.709 us; speedup vs baseline: 1.2626x; 1.0336x over previous
//
#include <hip/hip_runtime.h>
#include <math.h>

typedef __attribute__((ext_vector_type(8))) short short8;
typedef __attribute__((ext_vector_type(4))) float float4v;
typedef __attribute__((ext_vector_type(4))) unsigned short ushort4v;

static __device__ __forceinline__ unsigned short f2bf(float f) {
    union { float f; unsigned u; } v; v.f = f;
    unsigned u = v.u;
    return (unsigned short)((u + 0x7fffu + ((u >> 16) & 1u)) >> 16);
}
static __device__ __forceinline__ unsigned pk2(float a, float b) {
    return (unsigned)f2bf(a) | ((unsigned)f2bf(b) << 16);
}

// ---------------------------------------------------------------------------
// Graph structure (compile-time), matching Python enumeration order.
// ---------------------------------------------------------------------------
struct AdjT {
    int src[120];
    int dst[120];
    int cnt[36];
    int idx[36][4];
    int ostart[36];
    int ocnt[36];
};

constexpr AdjT build_adj() {
    AdjT a{};
    const int ddx[4] = {-1, 0, 0, 1};
    const int ddy[4] = {0, -1, 1, 0};
    int ne = 0;
    for (int i = 0; i < 6; i++)
        for (int j = 0; j < 6; j++)
            for (int d = 0; d < 4; d++) {
                int x = i + ddx[d], y = j + ddy[d];
                if (x >= 0 && x < 6 && y >= 0 && y < 6) {
                    a.src[ne] = j * 6 + i;
                    a.dst[ne] = y * 6 + x;
                    ne++;
                }
            }
    for (int n = 0; n < 36; n++) {
        a.cnt[n] = 0;
        for (int e = 0; e < 120; e++)
            if (a.dst[e] == n) a.idx[n][a.cnt[n]++] = e;
    }
    for (int n = 0; n < 36; n++) { a.ostart[n] = 0; a.ocnt[n] = 0; }
    for (int e = 0; e < 120; e++) {
        a.ocnt[a.src[e]]++;
        if (e == 0 || a.src[e] != a.src[e - 1]) a.ostart[a.src[e]] = e;
    }
    return a;
}

__device__ constexpr AdjT ADJC = build_adj();

// ---------------------------------------------------------------------------
// K0: merged prep (R21, unchanged). Blocks 0..31: composite conv1∘conv2 via
// register outer-product + shfl butterfly. Blocks 32..1319: B-frag prep.
// ---------------------------------------------------------------------------
__global__ __launch_bounds__(256) void k_prepall(
    const float* __restrict__ w1, const float* __restrict__ b1,
    const float* __restrict__ w2, const float* __restrict__ b2,
    const float* __restrict__ w3, const float* __restrict__ w4,
    const float* __restrict__ cnw1, const float* __restrict__ epw1,
    const float* __restrict__ cnw2, const float* __restrict__ epw2,
    unsigned short* __restrict__ wpc, float* __restrict__ wcb,
    unsigned short* __restrict__ wp3, unsigned short* __restrict__ wp4,
    unsigned short* __restrict__ wph1, unsigned short* __restrict__ wpcn2,
    unsigned short* __restrict__ wpep2) {
    __shared__ float s_w1[800];
    __shared__ float s_w2[800];
    if (blockIdx.x < 32) {
        const int co = blockIdx.x, tid = threadIdx.x;
        for (int i = tid; i < 800; i += 256) {
            s_w1[i] = w1[i];
            s_w2[i] = w2[co * 800 + i];
        }
        __syncthreads();
        if (tid < 64) {
            const int ci = tid & 31;
            float w1r[25], w2r[25];
#pragma unroll
            for (int o = 0; o < 25; o++) {
                w1r[o] = s_w1[ci * 25 + o];
                w2r[o] = s_w2[ci * 25 + o];
            }
            float acc[81];
#pragma unroll
            for (int i = 0; i < 81; i++) acc[i] = 0.f;
#pragma unroll
            for (int k1y = 0; k1y < 5; k1y++)
#pragma unroll
                for (int k1x = 0; k1x < 5; k1x++)
#pragma unroll
                    for (int k2y = 0; k2y < 5; k2y++)
#pragma unroll
                        for (int k2x = 0; k2x < 5; k2x++)
                            acc[(k1y + k2y) * 9 + (k1x + k2x)] +=
                                w1r[k1y * 5 + k1x] * w2r[k2y * 5 + k2x];
#pragma unroll
            for (int i = 0; i < 81; i++) {
                float v = acc[i];
                v += __shfl_xor(v, 1);
                v += __shfl_xor(v, 2);
                v += __shfl_xor(v, 4);
                v += __shfl_xor(v, 8);
                v += __shfl_xor(v, 16);
                acc[i] = v;
            }
            const int n = co >> 1, nt = co & 1;
#pragma unroll
            for (int t = 0; t < 128; t++) {
                const int ty = t / 12, tx = t - 12 * (t / 12);
                float val = (ty < 9 && tx < 9) ? acc[ty * 9 + tx] : 0.f;
                if ((tid & 63) == (t & 63)) {
                    int ks = t >> 5, r = t & 31, q = r >> 3, j = r & 7;
                    wpc[ks * 1024 + nt * 512 + (q * 16 + n) * 8 + j] = f2bf(val);
                }
            }
            float sw = 0.f;
#pragma unroll
            for (int o = 0; o < 25; o++) sw += w2r[o];
            float pb = b1[ci] * sw;
            pb += __shfl_xor(pb, 1);
            pb += __shfl_xor(pb, 2);
            pb += __shfl_xor(pb, 4);
            pb += __shfl_xor(pb, 8);
            pb += __shfl_xor(pb, 16);
            if (tid == 0) wcb[co] = b2[co] + pb;
        }
        return;
    }
    int e = (blockIdx.x - 32) * 256 + threadIdx.x;
    if (e < 51200) {
        int j = e & 7, lane = (e >> 3) & 63, nt = (e >> 9) & 3, t = e >> 11;
        int co = 4 * (lane & 15) + nt, ci = (lane >> 4) * 8 + j;
        wp3[e] = f2bf(w3[(co * 32 + ci) * 25 + t]);
    } else if (e < 153600) {
        int e4 = e - 51200;
        int j = e4 & 7, lane = (e4 >> 3) & 63, nt = (e4 >> 9) & 3;
        int ks = (e4 >> 11) & 1, t = e4 >> 12;
        int co = 4 * (lane & 15) + nt, ci = ks * 32 + (lane >> 4) * 8 + j;
        wp4[e4] = f2bf(w4[(co * 64 + ci) * 25 + t]);
    } else {
        int eh = e - 153600;
        if (eh < 131072) {
            int j = eh & 7, lane = (eh >> 3) & 63, nt = (eh >> 9) & 31, kt = eh >> 14;
            int c = nt * 16 + (lane & 15);
            int k = kt * 32 + ((lane >> 4) << 3) + j;
            float v = (c < 256) ? cnw1[c * 256 + k] : epw1[(c - 256) * 256 + k];
            wph1[eh] = f2bf(v);
        } else if (eh < 163840) {
            int e2 = eh - 131072;
            int j = e2 & 7, lane = (e2 >> 3) & 63, nt = (e2 >> 9) & 7, kt = e2 >> 12;
            int c = nt * 16 + (lane & 15);
            int k = kt * 32 + ((lane >> 4) << 3) + j;
            wpcn2[e2] = f2bf(c < 120 ? cnw2[c * 256 + k] : 0.f);
        } else {
            int e3 = eh - 163840;
            int j = e3 & 7, lane = (e3 >> 3) & 63, idx = e3 >> 9;
            int kt = idx / 3, nt = idx - kt * 3;
            int c = nt * 16 + (lane & 15);
            int k = kt * 32 + ((lane >> 4) << 3) + j;
            wpep2[e3] = f2bf(c < 36 ? epw2[c * 256 + k] : 0.f);
        }
    }
}

// ---------------------------------------------------------------------------
// K_CONVALL (R21, unchanged): R19 structure + 2-deep B-prefetch conv3/conv4.
// ---------------------------------------------------------------------------
#define REGSZ 10656
#define C3O 5760
#define CPY 1224

__global__ __launch_bounds__(512) void k_convall(
    const float* __restrict__ img,
    const unsigned short* __restrict__ wpc, const float* __restrict__ wcb,
    const unsigned short* __restrict__ wp3, const float* __restrict__ b3,
    const unsigned short* __restrict__ wp4, const float* __restrict__ b4,
    unsigned short* __restrict__ emb) {
    __shared__ __align__(16) unsigned short s_buf[2 * REGSZ];
    const int b2 = blockIdx.x, tid = threadIdx.x;
    const int lane = tid & 63, wave = tid >> 6;
    const int m = lane & 15, quad = lane >> 4;

    // ---- stage both images as 4 shifted bf16 copies (36-stride rows) ----
    {
        int simg = tid >> 8, t = tid & 255;
        float4 v = ((const float4*)(img + (size_t)(2 * b2 + simg) * 1024))[t];
        unsigned short pv[4];
        pv[0] = f2bf(v.x); pv[1] = f2bf(v.y);
        pv[2] = f2bf(v.z); pv[3] = f2bf(v.w);
        int r = t >> 3, x0 = (t & 7) * 4;
        int p36 = r * 36 + x0;
        unsigned short* reg = s_buf + simg * REGSZ + C3O;
#pragma unroll
        for (int c = 0; c < 4; c++)
#pragma unroll
            for (int i = 0; i < 4; i++) {
                int pos = p36 + i - c;
                if (pos >= 0) reg[c * CPY + pos] = pv[i];
            }
    }
    // zero-fill pad cols (x 32..35, r<32) + virtual rows 32..33 in all copies
    if (tid < 400) {
        int simg = tid >= 200, zz = tid - 200 * simg;
        int r, x;
        if (zz < 128) { r = zz >> 2; x = 32 + (zz & 3); }
        else { int rr = zz - 128; r = 32 + (rr >= 36 ? 1 : 0); x = rr - (rr >= 36 ? 36 : 0); }
        int p36 = r * 36 + x;
        unsigned short* reg = s_buf + simg * REGSZ + C3O;
#pragma unroll
        for (int c = 0; c < 4; c++) {
            int pos = p36 - c;
            if (pos >= 0 && pos < CPY) reg[c * CPY + pos] = 0;
        }
    }

    // composite-conv B-frags (4 K-steps, held in regs) + bias + A offsets
    const short8* wqc = (const short8*)wpc;
    short8 cb0[4], cb1[4];
#pragma unroll
    for (int ks = 0; ks < 4; ks++) {
        cb0[ks] = wqc[(ks * 2 + 0) * 64 + lane];
        cb1[ks] = wqc[(ks * 2 + 1) * 64 + lane];
    }
    const float bc0 = wcb[2 * m], bc1 = wcb[2 * m + 1];
    int ct1[4], ct2[4];
#pragma unroll
    for (int ks = 0; ks < 4; ks++) {
        int t0 = ks * 32 + quad * 8;
        ct1[ks] = (t0 / 12) * 36 + (t0 % 12);
        int t4 = t0 + 4;
        ct2[ks] = (t4 / 12) * 36 + (t4 % 12);
    }
    const short8* wq3 = (const short8*)wp3;

    __syncthreads();

    // ---- composite conv + in-register pool -> p2 [144][40] x 2 images ----
    for (int TT = wave; TT < 72; TT += 8) {
        int ci = TT >= 36 ? 1 : 0;
        int T = TT - 36 * ci;
        int pg = T * 4 + (m >> 2);            // pooled output index 0..143
        int py = (pg * 171) >> 11;            // == pg/12 for pg<144
        int px = pg - py * 12;
        int albase = (2 * py + ((m & 3) >> 1)) * 36 + 2 * px + (m & 1);
        const unsigned short* reg = s_buf + ci * REGSZ + C3O;
        float4v a0 = {0.f, 0.f, 0.f, 0.f};
        float4v a1 = {0.f, 0.f, 0.f, 0.f};
#pragma unroll
        for (int ks = 0; ks < 4; ks++) {
            int a = albase + ct1[ks];
            int c = a & 3;
            ushort4v lo = *(const ushort4v*)(reg + c * CPY + (a - c));
            a = albase + ct2[ks];
            c = a & 3;
            ushort4v hi = *(const ushort4v*)(reg + c * CPY + (a - c));
            short8 av;
            av[0] = (short)lo[0]; av[1] = (short)lo[1];
            av[2] = (short)lo[2]; av[3] = (short)lo[3];
            av[4] = (short)hi[0]; av[5] = (short)hi[1];
            av[6] = (short)hi[2]; av[7] = (short)hi[3];
            a0 = __builtin_amdgcn_mfma_f32_16x16x32_bf16(av, cb0[ks], a0, 0, 0, 0);
            a1 = __builtin_amdgcn_mfma_f32_16x16x32_bf16(av, cb1[ks], a1, 0, 0, 0);
        }
        float mx0 = fmaxf(fmaxf(a0[0], a0[1]), fmaxf(a0[2], a0[3])) + bc0;
        float mx1 = fmaxf(fmaxf(a1[0], a1[1]), fmaxf(a1[2], a1[3])) + bc1;
        int row = T * 4 + quad;
        *(unsigned*)(s_buf + ci * REGSZ + row * 40 + 2 * m) = pk2(mx0, mx1);
    }
    __syncthreads();

    // ---- conv3: wave = (img, Mtile-pair, Ntile-pair); 2-deep B-prefetch ----
    {
        const int img3 = wave >> 2;
        const int mt0 = ((wave >> 1) & 1) * 2;
        const int nt0 = (wave & 1) * 2;
        const unsigned short* sb = s_buf + img3 * REGSZ;
        int a3[2];
#pragma unroll
        for (int mi = 0; mi < 2; mi++) {
            int pos3 = (mt0 + mi) * 16 + m;
            int y3 = pos3 >> 3, x3 = pos3 & 7;
            a3[mi] = (y3 * 12 + x3) * 40 + quad * 8;
        }
        float4v acc3[2][2];
#pragma unroll
        for (int mi = 0; mi < 2; mi++)
#pragma unroll
            for (int ni = 0; ni < 2; ni++)
                acc3[mi][ni] = (float4v){0.f, 0.f, 0.f, 0.f};
        short8 bA0 = wq3[(0 * 4 + nt0) * 64 + lane];
        short8 bA1 = wq3[(0 * 4 + nt0 + 1) * 64 + lane];
        short8 bB0 = wq3[(1 * 4 + nt0) * 64 + lane];
        short8 bB1 = wq3[(1 * 4 + nt0 + 1) * 64 + lane];
        for (int t = 0; t < 25; t++) {
            short8 bC0, bC1;
            if (t < 23) {
                bC0 = wq3[((t + 2) * 4 + nt0) * 64 + lane];
                bC1 = wq3[((t + 2) * 4 + nt0 + 1) * 64 + lane];
            }
            const int ky = t / 5, kx = t - ky * 5;
            const int toff = (ky * 12 + kx) * 40;
            short8 av0 = *(const short8*)(sb + a3[0] + toff);
            short8 av1 = *(const short8*)(sb + a3[1] + toff);
            acc3[0][0] = __builtin_amdgcn_mfma_f32_16x16x32_bf16(av0, bA0, acc3[0][0], 0, 0, 0);
            acc3[0][1] = __builtin_amdgcn_mfma_f32_16x16x32_bf16(av0, bA1, acc3[0][1], 0, 0, 0);
            acc3[1][0] = __builtin_amdgcn_mfma_f32_16x16x32_bf16(av1, bA0, acc3[1][0], 0, 0, 0);
            acc3[1][1] = __builtin_amdgcn_mfma_f32_16x16x32_bf16(av1, bA1, acc3[1][1], 0, 0, 0);
            bA0 = bB0; bA1 = bB1;
            if (t < 23) { bB0 = bC0; bB1 = bC1; }
        }
        float bb0 = b3[4 * m + nt0], bb1 = b3[4 * m + nt0 + 1];
#pragma unroll
        for (int mi = 0; mi < 2; mi++)
#pragma unroll
            for (int r = 0; r < 4; r++) {
                int row3 = (mt0 + mi) * 16 + quad * 4 + r;
                *(unsigned*)(s_buf + img3 * REGSZ + C3O + row3 * 72 + 4 * m + nt0) =
                    pk2(acc3[mi][0][r] + bb0, acc3[mi][1][r] + bb1);
            }
    }
    __syncthreads();

    // ---- conv4: wave = (img, Ntile); 2-deep B-prefetch ----
    {
        const int img4 = wave >> 2, nt4 = wave & 3;
        int y4 = m >> 2, x4 = m & 3;
        const unsigned short* sb = s_buf + img4 * REGSZ;
        int a4 = C3O + (y4 * 8 + x4) * 72 + quad * 8;
        float4v acc4 = (float4v){0.f, 0.f, 0.f, 0.f};
        const short8* wq4 = (const short8*)wp4;
        short8 cA0 = wq4[((0 * 2 + 0) * 4 + nt4) * 64 + lane];
        short8 cA1 = wq4[((0 * 2 + 1) * 4 + nt4) * 64 + lane];
        short8 cB0 = wq4[((1 * 2 + 0) * 4 + nt4) * 64 + lane];
        short8 cB1 = wq4[((1 * 2 + 1) * 4 + nt4) * 64 + lane];
        for (int t = 0; t < 25; t++) {
            short8 cC0, cC1;
            if (t < 23) {
                cC0 = wq4[(((t + 2) * 2 + 0) * 4 + nt4) * 64 + lane];
                cC1 = wq4[(((t + 2) * 2 + 1) * 4 + nt4) * 64 + lane];
            }
            const int ky = t / 5, kx = t - ky * 5;
            const int toff = (ky * 8 + kx) * 72;
            short8 av0 = *(const short8*)(sb + a4 + toff);
            acc4 = __builtin_amdgcn_mfma_f32_16x16x32_bf16(av0, cA0, acc4, 0, 0, 0);
            short8 av1 = *(const short8*)(sb + a4 + toff + 32);
            acc4 = __builtin_amdgcn_mfma_f32_16x16x32_bf16(av1, cA1, acc4, 0, 0, 0);
            cA0 = cB0; cA1 = cB1;
            if (t < 23) { cB0 = cC0; cB1 = cC1; }
        }
        float* s_c4 = (float*)(s_buf + img4 * REGSZ);
#pragma unroll
        for (int r = 0; r < 4; r++)
            s_c4[(quad * 4 + r) * 68 + 4 * m + nt4] = acc4[r];
    }
    __syncthreads();

    // emb epilogue: tid = img*256 + co*4 + pp; pool 2x2 + bias4 + flatten
    {
        const int simg = tid >> 8, t = tid & 255;
        const float* s_c4 = (const float*)(s_buf + simg * REGSZ);
        int co = t >> 2, pp = t & 3;
        int ppy = pp >> 1, ppx = pp & 1;
        float v0 = s_c4[((2 * ppy) * 4 + 2 * ppx) * 68 + co];
        float v1 = s_c4[((2 * ppy) * 4 + 2 * ppx + 1) * 68 + co];
        float v2 = s_c4[((2 * ppy + 1) * 4 + 2 * ppx) * 68 + co];
        float v3 = s_c4[((2 * ppy + 1) * 4 + 2 * ppx + 1) * 68 + co];
        emb[(size_t)(2 * b2 + simg) * 256 + t] =
            f2bf(fmaxf(fmaxf(v0, v1), fmaxf(v2, v3)) + b4[co]);
    }
}

// ---------------------------------------------------------------------------
// K5 (R22): 4 IMAGES PER BLOCK, 512 thr, grid = B/4 = 256 (full CU coverage,
// was 64 blocks / 25%). MFMA M-rows 4..15 compute garbage for rows of
// neighboring images — contamination stays in C rows 4..15, never read by
// phase 3 (w<4). emb A-row index clamped to B-1 (tail blocks). Phase1: 32
// N-tiles over 8 waves (4 each); phase2: 11 jobs over 8 waves (w, w+8);
// phase3: waves 0..3, one image each (register/shuffle recurrence).
// ---------------------------------------------------------------------------
__global__ __launch_bounds__(512) void k_heads(
    const unsigned short* __restrict__ emb,
    const unsigned short* __restrict__ wph1,
    const float* __restrict__ cn_b1, const float* __restrict__ ep_b1,
    const unsigned short* __restrict__ wpcn2, const float* __restrict__ cn_b2,
    const unsigned short* __restrict__ wpep2, const float* __restrict__ ep_b2,
    float* __restrict__ out, int B) {
    __shared__ unsigned short s_hid[16 * 520];
    __shared__ float s_conn[120 * 17];
    __shared__ float s_ep[36 * 17];
    const int tid = threadIdx.x;
    const int lane = tid & 63, wave = tid >> 6;
    const int m = lane & 15, q = lane >> 4;
    const int b0 = blockIdx.x * 4;

    // ---- phase 1: hid = relu(emb @ W1^T + b1), 512 cols over 8 waves ----
    float4v acc[4];
#pragma unroll
    for (int i = 0; i < 4; i++) acc[i] = (float4v){0.f, 0.f, 0.f, 0.f};
    const short8* wp1 = (const short8*)wph1;
    int arow = b0 + m;
    if (arow >= B) arow = B - 1;   // tail clamp (rows 4..15 unused anyway)
    for (int kt = 0; kt < 8; kt++) {
        short8 av = *(const short8*)(emb + (size_t)arow * 256 + kt * 32 + q * 8);
#pragma unroll
        for (int ntl = 0; ntl < 4; ntl++) {
            int nt = wave * 4 + ntl;
            short8 bv = wp1[(kt * 32 + nt) * 64 + lane];
            acc[ntl] = __builtin_amdgcn_mfma_f32_16x16x32_bf16(av, bv, acc[ntl], 0, 0, 0);
        }
    }
#pragma unroll
    for (int ntl = 0; ntl < 4; ntl++) {
        int c = (wave * 4 + ntl) * 16 + m;
        float bb = (c < 256) ? cn_b1[c] : ep_b1[c - 256];
#pragma unroll
        for (int r = 0; r < 4; r++)
            s_hid[(q * 4 + r) * 520 + c] = f2bf(fmaxf(acc[ntl][r] + bb, 0.f));
    }
    __syncthreads();

    // ---- phase 2: conn (8 jobs) + ep (3 jobs) over 8 waves ----
    for (int job = wave; job < 11; job += 8) {
        const bool isconn = job < 8;
        const int koff = isconn ? 0 : 256;
        float4v a2 = (float4v){0.f, 0.f, 0.f, 0.f};
        for (int kt = 0; kt < 8; kt++) {
            short8 av = *(const short8*)(s_hid + m * 520 + koff + kt * 32 + q * 8);
            short8 bv = isconn
                ? ((const short8*)wpcn2)[(kt * 8 + job) * 64 + lane]
                : ((const short8*)wpep2)[(kt * 3 + (job - 8)) * 64 + lane];
            a2 = __builtin_amdgcn_mfma_f32_16x16x32_bf16(av, bv, a2, 0, 0, 0);
        }
        int c = (isconn ? job : (job - 8)) * 16 + m;
        float bb = isconn ? (c < 120 ? cn_b2[c] : 0.f) : (c < 36 ? ep_b2[c] : 0.f);
#pragma unroll
        for (int r = 0; r < 4; r++) {
            float v = 1.f / (1.f + __expf(-(a2[r] + bb)));
            int row = q * 4 + r;
            if (isconn) {
                if (c < 120) s_conn[c * 17 + row] = v;
            } else {
                if (c < 36) s_ep[c * 17 + row] = v;
            }
        }
    }
    __syncthreads();

    // ---- phase 3: register/shuffle node-state recurrence, img = wave<4 ----
    if (wave < 4) {
        const int w = wave;          // image index within block
        const int n = lane;          // node index (active n < 36)
        int msrc[4];
        float cr[4];
        const int cnt = (n < 36) ? ADJC.cnt[n] : 0;
#pragma unroll
        for (int k = 0; k < 4; k++) {
            if (n < 36 && k < cnt) {
                int e = ADJC.idx[n][k];
                msrc[k] = ADJC.src[e];
                cr[k] = s_conn[e * 17 + w];
            } else {
                msrc[k] = 0;
                cr[k] = 0.f;
            }
        }
        float S = fminf(cr[0] + cr[1] + cr[2] + cr[3], 1.f);
        const float conn0 = s_conn[0 * 17 + w];
        float old0 = conn0;
        for (int it = 0; it < 36; it++) {
            float s0 = __shfl(S, 0);
            float g0 = __shfl(S, msrc[0]);
            float g1 = __shfl(S, msrc[1]);
            float g2 = __shfl(S, msrc[2]);
            float g3 = __shfl(S, msrc[3]);
            old0 = fminf(old0 + s0 * conn0, 1.f);
            S = fminf(g0 * cr[0] + g1 * cr[1] + g2 * cr[2] + g3 * cr[3], 1.f);
        }
        if (lane == 0)
            out[b0 + w] = old0 * s_ep[0 * 17 + w] * s_ep[6 * 17 + w];
    }
}

// ---------------------------------------------------------------------------
extern "C" void kernel_launch(void* const* d_in, const int* in_sizes, int n_in,
                              void* d_out, int out_size, void* d_ws, size_t ws_size,
                              hipStream_t stream) {
    const float* image = (const float*)d_in[0];
    const float* c1w = (const float*)d_in[1];
    const float* c1b = (const float*)d_in[2];
    const float* c2w = (const float*)d_in[3];
    const float* c2b = (const float*)d_in[4];
    const float* c3w = (const float*)d_in[5];
    const float* c3b = (const float*)d_in[6];
    const float* c4w = (const float*)d_in[7];
    const float* c4b = (const float*)d_in[8];
    const float* epw1 = (const float*)d_in[9];
    const float* epb1 = (const float*)d_in[10];
    const float* epw2 = (const float*)d_in[11];
    const float* epb2 = (const float*)d_in[12];
    const float* cnw1 = (const float*)d_in[13];
    const float* cnb1 = (const float*)d_in[14];
    const float* cnw2 = (const float*)d_in[15];
    const float* cnb2 = (const float*)d_in[16];

    const int B = in_sizes[0] / (32 * 32);  // 1024

    unsigned short* ws = (unsigned short*)d_ws;
    unsigned short* embo = ws;                            // B*256 bf16
    unsigned short* wp3 = embo + (size_t)B * 256;         // 51200
    unsigned short* wp4 = wp3 + 51200;                    // 102400
    unsigned short* wph1 = wp4 + 102400;                  // 131072
    unsigned short* wpcn2 = wph1 + 131072;                // 32768
    unsigned short* wpep2 = wpcn2 + 32768;                // 12288
    unsigned short* wpc = wpep2 + 12288;                  // 4096 (K=128)
    float* wcb = (float*)(wpc + 4096);                    // 32 f32

    k_prepall<<<1320, 256, 0, stream>>>(c1w, c1b, c2w, c2b, c3w, c4w,
                                        cnw1, epw1, cnw2, epw2,
                                        wpc, wcb, wp3, wp4, wph1, wpcn2, wpep2);
    k_convall<<<B / 2, 512, 0, stream>>>(image, wpc, wcb, wp3, c3b, wp4, c4b, embo);
    k_heads<<<B / 4, 512, 0, stream>>>(embo, wph1, cnb1, epb1,
                                       wpcn2, cnb2, wpep2, epb2, (float*)d_out, B);
}